// Round 8
// baseline (196.884 us; speedup 1.0000x reference)
//
#include <hip/hip_runtime.h>

// WaveNet inference on MFMA. Exploits: (1) only last timestep feeds the FC
// head, (2) skip overwritten each layer (only layer 15's matters),
// (3) receptive field at t=T-1 is 77 steps.
// Round 21 = R20 +
//  - TAIL WEIGHT WARMING: waves 1-3 (idle during reg layers L10-15) touch
//    every cache line of end1/end2/fc1-4/skip[L15] weights + all tail
//    biases (832KB+4KB = ~13.4K lines, 12 loads/thread/layer), summed into
//    a reg kept alive via asm(""::"v") -- per-dispatch cold HBM misses
//    (~900cy x 7 serial stages) become L2 hits (~200cy).
//  - bias load hoisted to top of every tail stage (was a dependent load
//    AFTER the reduce, right before the store the next barrier waits on).
// Regime rules learned (R3/4: >256 thr spills; R8: never trade CUs for
// waves; R9/R11: no serial work to kill barriers; R12: reg plumbing ~ LDS;
// R14: staging off compute waves ~neutral; R15/R16: dependent hops on the
// critical wave are the chain; R17: never ship unverifiable asm semantics;
// R19: tail weight-read coalescing -8%; R20: tail reduce flavor ~neutral
// -> tail is latency-bound, not ALU-bound; FETCH 6MB/dispatch = cold every
// dispatch, L3 does not persist across launches).

#define BB 16
#define TT 8192
#define LL 16
#define W0 77
#define NT 256

typedef __attribute__((ext_vector_type(8)))  short short8;
typedef __attribute__((ext_vector_type(16))) float float16;
typedef __attribute__((ext_vector_type(2)))  unsigned uv2;

#define MFMA_B16(a, b, c) __builtin_amdgcn_mfma_f32_32x32x16_bf16(a, b, c, 0, 0, 0)

__device__ __forceinline__ short f2bs(float f) {   // f32 -> bf16 bits, RNE
  union { float ff; unsigned u; } v; v.ff = f;
  unsigned u = v.u;
  return (short)((u + 0x7FFFu + ((u >> 16) & 1u)) >> 16);
}
__device__ __forceinline__ float b2f(short h) {
  union { unsigned u; float f; } v;
  v.u = ((unsigned)(unsigned short)h) << 16; return v.f;
}
__device__ __forceinline__ unsigned cvtpk(float lo, float hi) {
  unsigned r;
  asm("v_cvt_pk_bf16_f32 %0, %1, %2" : "=v"(r) : "v"(lo), "v"(hi));
  return r;
}
__device__ __forceinline__ short8 mk8(unsigned a, unsigned b, unsigned c, unsigned d) {
  union { unsigned u[4]; short8 s; } z;
  z.u[0] = a; z.u[1] = b; z.u[2] = c; z.u[3] = d; return z.s;
}
__device__ __forceinline__ float u2f(unsigned u) {
  union { unsigned x; float f; } z; z.x = u; return z.f;
}

// DPP-assisted lane-group sums (probe-verified; shfl fallback).
__device__ __forceinline__ float dpp_add(float x, const int ctrl_sel) {
  int xi = __float_as_int(x);
  int m;
  if (ctrl_sel == 0)      m = __builtin_amdgcn_update_dpp(0, xi, 0xB1,  0xF, 0xF, true);
  else if (ctrl_sel == 1) m = __builtin_amdgcn_update_dpp(0, xi, 0x4E,  0xF, 0xF, true);
  else if (ctrl_sel == 2) m = __builtin_amdgcn_update_dpp(0, xi, 0x124, 0xF, 0xF, true);
  else if (ctrl_sel == 3) m = __builtin_amdgcn_update_dpp(0, xi, 0x128, 0xF, 0xF, true);
  else                    m = __builtin_amdgcn_update_dpp(0, xi, 0x141, 0xF, 0xF, true);
  return x + __int_as_float(m);
}
__device__ __forceinline__ float row16_sum(float x, bool dpp) {
  if (dpp) {
    x = dpp_add(x, 0); x = dpp_add(x, 1); x = dpp_add(x, 2); x = dpp_add(x, 3);
  } else {
    #pragma unroll
    for (int d2 = 1; d2 < 16; d2 <<= 1) x += __shfl_xor(x, d2);
  }
  return x;
}
__device__ __forceinline__ float row8_sum(float x, bool dpp) {
  if (dpp) {
    x = dpp_add(x, 0); x = dpp_add(x, 1); x = dpp_add(x, 4);
  } else {
    #pragma unroll
    for (int d2 = 1; d2 < 8; d2 <<= 1) x += __shfl_xor(x, d2);
  }
  return x;
}

// D'-words -> B-frag words via cross-half words cr (cr[q] = own[q] from l^32).
__device__ __forceinline__ void asmb(const unsigned* own, const unsigned* cr,
                                     int kh, unsigned* o) {
  #pragma unroll
  for (int h = 0; h < 2; h++) {
    o[4*h+0] = kh ? cr[4*h+2] : own[4*h+0];
    o[4*h+1] = kh ? cr[4*h+3] : own[4*h+1];
    o[4*h+2] = kh ? own[4*h+2] : cr[4*h+0];
    o[4*h+3] = kh ? own[4*h+3] : cr[4*h+1];
  }
}

// In-place half-exchange of 8 words. mode 0/1: permlane32_swap builtin
// (either return order); mode 2: __shfl fallback (exact R16 path).
__device__ __forceinline__ void exch(unsigned* o, int kh, int lx32, int mode) {
  if (mode < 2) {
    #pragma unroll
    for (int h = 0; h < 2; h++)
      #pragma unroll
      for (int j = 0; j < 2; j++) {
        unsigned A = o[4*h+j], C = o[4*h+2+j];
        uv2 r = __builtin_amdgcn_permlane32_swap(A, C, false, false);
        o[4*h+j]   = (mode == 0) ? r[0] : r[1];
        o[4*h+2+j] = (mode == 0) ? r[1] : r[0];
      }
  } else {
    unsigned cr[8];
    #pragma unroll
    for (int q = 0; q < 8; q++) cr[q] = (unsigned)__shfl((int)o[q], lx32);
    unsigned t[8];
    asmb(o, cr, kh, t);
    #pragma unroll
    for (int q = 0; q < 8; q++) o[q] = t[q];
  }
}

// A-fragment halves from [row][32] bf16 LDS: A[m][k], k-local=(lane>>5)*8+j.
__device__ __forceinline__ void afrag2(const short* src, int row, int kh, short8* out) {
  out[0] = *(const short8*)&src[row * 32 + 8 * kh];
  out[1] = *(const short8*)&src[row * 32 + 16 + 8 * kh];
}

// load a full row's 8 packed words (B-frag layout) from [row][32] bf16 LDS
__device__ __forceinline__ void ldrow(const short* xb, int row, int kh, unsigned* w8) {
  #pragma unroll
  for (int h = 0; h < 2; h++) {
    short8 v = *(const short8*)&xb[row * 32 + 16 * h + 8 * kh];
    union { short8 s; unsigned u[4]; } z; z.s = v;
    #pragma unroll
    for (int s = 0; s < 4; s++) w8[4 * h + s] = z.u[s];
  }
}

// chunk cid in [0,896): mat=cid>>7, h=(cid>>6)&1, ln=cid&63 -> n=ln&31,k2=ln>>5
__device__ __forceinline__ void load_chunk(
    int li, int cid, float* pf,
    const float* dil_w, const float* filt_w, const float* gate_w, const float* res_w)
{
  int mat = cid >> 7;
  int h = (cid >> 6) & 1, ln = cid & 63;
  int n = ln & 31, k2 = ln >> 5;
  int base = (li * 32 + n) * 32 + 16 * h + 8 * k2;
  if (mat == 6) {
    const float* p = res_w + base;
    #pragma unroll
    for (int j = 0; j < 8; j++) pf[j] = p[j];
  } else {
    const float* w = (mat < 2) ? dil_w : (mat < 4) ? filt_w : gate_w;
    const float* p = w + base * 2 + (mat & 1);
    #pragma unroll
    for (int j = 0; j < 8; j++) pf[j] = p[2 * j];
  }
}

// stage one reg-path layer's frags+bias (staging waves, ptid in [0,192))
__device__ __forceinline__ void stage_layer(
    int li, int ptid, short* dst, float* bdst,
    const float* dil_w, const float* filt_w, const float* gate_w, const float* res_w,
    const float* dil_b, const float* filt_b, const float* gate_b, const float* res_b)
{
  float pf[5][8];
  #pragma unroll
  for (int q = 0; q < 5; q++) {
    int c = ptid + q * 192;
    if (c < 896) load_chunk(li, c, pf[q], dil_w, filt_w, gate_w, res_w);
  }
  #pragma unroll
  for (int q = 0; q < 5; q++) {
    int c = ptid + q * 192;
    if (c < 896) {
      short8 v;
      #pragma unroll
      for (int j = 0; j < 8; j++) v[j] = f2bs(pf[q][j]);
      *(short8*)&dst[c * 8] = v;
    }
  }
  for (int t2 = ptid; t2 < 128; t2 += 192) {
    const float* bsrc = (t2 < 32) ? dil_b : (t2 < 64) ? filt_b : (t2 < 96) ? gate_b : res_b;
    bdst[t2] = bsrc[li * 32 + (t2 & 31)];
  }
}

// Touch one f32 per 64B line of the tail weight regions (832KB = 13312
// lines over 6 layers x 192 threads x 12 loads). Read-only; result kept
// alive by caller via asm. Warms L2/L3 ahead of the serial tail.
__device__ __forceinline__ float warm_lines(
    int li, int ptid,
    const float* end1_w, const float* end2_w, const float* fc1_w,
    const float* fc2_w, const float* fc3_w, const float* fc4_w,
    const float* skip_w)
{
  float s = 0.f;
  #pragma unroll
  for (int j = 0; j < 12; j++) {
    int gid = (li * 12 + j) * 192 + ptid;
    if (gid < 13312) {
      int off = gid * 16;
      const float* p;
      if      (off < 65536)  p = end1_w + off;
      else if (off < 131072) p = end2_w + (off - 65536);
      else if (off < 163840) p = fc1_w + (off - 131072);
      else if (off < 180224) p = fc2_w + (off - 163840);
      else if (off < 188416) p = fc3_w + (off - 180224);
      else if (off < 204800) p = fc4_w + (off - 188416);
      else                   p = skip_w + 15 * 256 * 32 + (off - 204800);
      s += *p;
    }
  }
  return s;
}
__device__ __forceinline__ float warm_bias(int ptid,
    const float* end1_b, const float* end2_b, const float* fc1_b,
    const float* fc2_b, const float* fc3_b, const float* fc4_b,
    const float* skip_b)
{
  if (ptid >= 84) return 0.f;
  int off = ptid * 16;
  const float* p;
  if      (off < 256)  p = end1_b + off;
  else if (off < 512)  p = end2_b + (off - 256);
  else if (off < 640)  p = fc1_b + (off - 512);
  else if (off < 768)  p = fc2_b + (off - 640);
  else if (off < 832)  p = fc3_b + (off - 768);
  else if (off < 1088) p = fc4_b + (off - 832);
  else                 p = skip_b + 15 * 256 + (off - 1088);
  return *p;
}

// Coalesced split-K matvec stage: W[R][K] row-major, vin LDS f32[K].
// Bias load hoisted to stage top (off the post-reduce critical path).
template<int R, int K, bool RELU>
__device__ __forceinline__ void mv_stage(const float* __restrict__ W,
                                         const float* __restrict__ bias,
                                         const float* vin, float* vout,
                                         int tid, bool dpp)
{
  constexpr int J = K >> 6;                 // float4 groups per pass
  constexpr int P = R >> 4;                 // passes (rows/16)
  const int s = tid & 15, rb = tid >> 4;
  const int ro = rb + 16 * (s & (P - 1));   // in-bounds for all threads
  const float bb = bias[ro];                // hoisted bias (issued early)
  float4 vf[J];
  #pragma unroll
  for (int j = 0; j < J; j++) vf[j] = *(const float4*)&vin[(s + 16 * j) * 4];
  float part[P];
  #pragma unroll
  for (int p = 0; p < P; p++) {
    const float* wr = W + (rb + 16 * p) * K;
    float a = 0.f, c = 0.f;
    #pragma unroll
    for (int j = 0; j < J; j++) {
      float4 w = *(const float4*)&wr[(s + 16 * j) * 4];
      a += w.x * vf[j].x + w.y * vf[j].y;
      c += w.z * vf[j].z + w.w * vf[j].w;
    }
    part[p] = a + c;
  }
  #pragma unroll
  for (int p = 0; p < P; p++) part[p] = row16_sum(part[p], dpp);
  if (s < P) {
    float val = part[0];
    #pragma unroll
    for (int p = 1; p < P; p++) val = (s == p) ? part[p] : val;
    float r2 = val + bb;
    if (RELU) r2 = fmaxf(r2, 0.f);
    vout[ro] = r2;
  }
}

__global__ __launch_bounds__(NT, 1) void wavenet_kernel(
    const int* __restrict__ tokens,
    const float* __restrict__ emb,
    const float* __restrict__ init_w, const float* __restrict__ init_b,
    const float* __restrict__ dil_w,  const float* __restrict__ dil_b,
    const float* __restrict__ filt_w, const float* __restrict__ filt_b,
    const float* __restrict__ gate_w, const float* __restrict__ gate_b,
    const float* __restrict__ res_w,  const float* __restrict__ res_b,
    const float* __restrict__ skip_w, const float* __restrict__ skip_b,
    const float* __restrict__ end1_w, const float* __restrict__ end1_b,
    const float* __restrict__ end2_w, const float* __restrict__ end2_b,
    const float* __restrict__ fc1_w,  const float* __restrict__ fc1_b,
    const float* __restrict__ fc2_w,  const float* __restrict__ fc2_b,
    const float* __restrict__ fc3_w,  const float* __restrict__ fc3_b,
    const float* __restrict__ fc4_w,  const float* __restrict__ fc4_b,
    float* __restrict__ out)
{
  __shared__ __align__(16) short bfw[2][7168];   // weight frags, double buffer
  __shared__ __align__(16) float bias2[2][128];
  __shared__ __align__(16) short xbuf[2][W0 * 32];  // activation double buffer
  __shared__ __align__(16) short pool[8624];     // emb stage / rb+xm / L14 slot
  __shared__ int tok[W0];
  __shared__ __align__(16) float vecA[256], vecB[256];

  short* rb = pool;          // 76*32 (LDS layers)
  short* xm = pool + 2432;   // 76*32 (LDS layers)
  short* l14w = pool;                      // L14 frag slot (reg path)
  float* l14b = (float*)&pool[7168];       // L14 bias slot (128 f32)

  const int tid  = threadIdx.x;
  const int lane = tid & 63;
  const int wv   = tid >> 6;
  const int m    = lane & 31;
  const int kh   = lane >> 5;
  const int b    = blockIdx.x;

  // ---- probe DPP reduce semantics (uniform; exact integer sums) ----
  bool dpp;
  {
    float s16 = row16_sum((float)((tid & 15) + 1), true);   // want 136
    float s8v = row8_sum((float)((tid & 7) + 1), true);     // want 36
    dpp = (bool)__all((s16 == 136.0f) && (s8v == 36.0f));
  }

  // ---- tokens ----
  if (tid < W0) tok[tid] = tokens[b * TT + (TT - 1 - tid)];
  __syncthreads();

  // ---- stage emb rows (bf16, rows zero-padded to K=112) ----
  for (int cid = tid; cid < 77 * 14; cid += NT) {
    int u = cid / 14, s = cid % 14;
    const float* er = emb + tok[u] * 100 + s * 8;
    short8 v;
    if (s < 12) {
      #pragma unroll
      for (int j = 0; j < 8; j++) v[j] = f2bs(er[j]);
    } else if (s == 12) {
      #pragma unroll
      for (int j = 0; j < 4; j++) v[j] = f2bs(er[j]);
      #pragma unroll
      for (int j = 4; j < 8; j++) v[j] = 0;
    } else {
      #pragma unroll
      for (int j = 0; j < 8; j++) v[j] = 0;
    }
    *(short8*)&pool[u * 112 + s * 8] = v;
  }
  // stage layer-0 weight frags + biases directly (all threads)
  for (int cid = tid; cid < 896; cid += NT) {
    float pf[8];
    load_chunk(0, cid, pf, dil_w, filt_w, gate_w, res_w);
    short8 v;
    #pragma unroll
    for (int j = 0; j < 8; j++) v[j] = f2bs(pf[j]);
    *(short8*)&bfw[0][cid * 8] = v;
  }
  if (tid < 128) {
    const float* bsrc = (tid < 32) ? dil_b : (tid < 64) ? filt_b : (tid < 96) ? gate_b : res_b;
    bias2[0][tid] = bsrc[tid & 31];
  }
  __syncthreads();

  // ---- init conv (waves 0..2, one 32-row tile each, MFMA K=112, 4+3 split) ----
  if (wv < 3) {
    short8 bi[7];
    #pragma unroll
    for (int s = 0; s < 7; s++) {
      const float* p = init_w + m * 100 + s * 16 + kh * 8;
      short8 v;
      if (s < 6) {
        #pragma unroll
        for (int j = 0; j < 8; j++) v[j] = f2bs(p[j]);
      } else if (kh == 0) {
        #pragma unroll
        for (int j = 0; j < 4; j++) v[j] = f2bs(p[j]);
        #pragma unroll
        for (int j = 4; j < 8; j++) v[j] = 0;
      } else {
        #pragma unroll
        for (int j = 0; j < 8; j++) v[j] = 0;
      }
      bi[s] = v;
    }
    const float binit = init_b[m];
    const int R = wv * 32;
    int u = R + m; if (u > 76) u = 76;
    float16 accA, accB;
    #pragma unroll
    for (int r = 0; r < 16; r++) { accA[r] = binit; accB[r] = 0.f; }
    #pragma unroll
    for (int s = 0; s < 7; s++) {
      short8 a = *(const short8*)&pool[u * 112 + s * 16 + kh * 8];
      if (s < 4) accA = MFMA_B16(a, bi[s], accA);
      else       accB = MFMA_B16(a, bi[s], accB);
    }
    #pragma unroll
    for (int r = 0; r < 16; r++) {
      int row = (r & 3) + 8 * (r >> 2) + 4 * kh;
      int uu = R + row;
      if (uu < W0) xbuf[0][uu * 32 + m] = f2bs(accA[r] + accB[r]);
    }
  }
  __syncthreads();

  // ---- layers 0..9 (LDS pipeline, stride-31 overlapping tiles, 1 barrier) ----
  int Win = W0;
  for (int i = 0; i < 10; i++) {
    const int d = 1 << (i & 3);
    const int Wout = Win - d - 1;
    const int T = (Wout + 31) / 31;
    const short* bw = bfw[i & 1];
    const float* bs = bias2[i & 1];
    const short* xin  = xbuf[i & 1];
    short* xout = xbuf[(i + 1) & 1];

    float pfo[4][8];
    float pbias = 0.f;
    const int nch = (tid < 128) ? 4 : 3;   // 896 = 3*256 + 128
    const bool oldpf = (T >= 3) && (i + 1 < LL);
    if (oldpf) {
      #pragma unroll
      for (int q = 0; q < 4; q++) {
        if (q < nch)
          load_chunk(i + 1, tid + q * NT, pfo[q], dil_w, filt_w, gate_w, res_w);
      }
      if (tid < 128) {
        const float* bsrc = (tid < 32) ? dil_b : (tid < 64) ? filt_b : (tid < 96) ? gate_b : res_b;
        pbias = bsrc[(i + 1) * 32 + (tid & 31)];
      }
    }
    const bool newpf = (T <= 2) && (i + 1 < LL) && (wv >= T);
    const int nP = NT - T * 64;
    const int ptid = tid - T * 64;
    float pfn[7][8];
    if (newpf) {
      #pragma unroll
      for (int q = 0; q < 7; q++) {
        int c = ptid + q * nP;
        if (c < 896) load_chunk(i + 1, c, pfn[q], dil_w, filt_w, gate_w, res_w);
      }
    }

    if (wv < T) {
      const int R = wv * 31;
      short8 B0[2], B1[2], BW[5][2];
      #pragma unroll
      for (int h = 0; h < 2; h++) {
        B0[h] = *(const short8*)&bw[((0 * 2 + h) * 64 + lane) * 8];
        B1[h] = *(const short8*)&bw[((1 * 2 + h) * 64 + lane) * 8];
      }
      #pragma unroll
      for (int mt = 0; mt < 5; mt++)
        #pragma unroll
        for (int h = 0; h < 2; h++)
          BW[mt][h] = *(const short8*)&bw[(((mt + 2) * 2 + h) * 64 + lane) * 8];

      // ---- phase1: rb rows R..R+31 (2+2 split chains) ----
      int vra = R + m + d; if (vra > Win - 1) vra = Win - 1;
      int vrz = R + m;     if (vrz > Win - 1) vrz = Win - 1;
      short8 aA[2], aZ[2];
      afrag2(xin, vra, kh, aA);
      afrag2(xin, vrz, kh, aZ);
      float16 p1a, p1b;
      const float bc = bs[m];
      #pragma unroll
      for (int r = 0; r < 16; r++) { p1a[r] = bc; p1b[r] = 0.f; }
      p1a = MFMA_B16(aA[0], B0[0], p1a);
      p1a = MFMA_B16(aA[1], B0[1], p1a);
      p1b = MFMA_B16(aZ[0], B1[0], p1b);
      p1b = MFMA_B16(aZ[1], B1[1], p1b);
      #pragma unroll
      for (int r = 0; r < 16; r++) {
        int row = (r & 3) + 8 * (r >> 2) + 4 * kh;
        int vr = R + row;
        if (vr <= Wout) rb[vr * 32 + m] = f2bs(p1a[r] + p1b[r]);
      }
      asm volatile("s_waitcnt lgkmcnt(0)" ::: "memory");  // wave-local P1->P2

      // ---- phase2: f/g convs (2+2 splits); hoisted phase3 C-init ----
      const int capA = (R + 31 < Wout) ? (R + 31) : Wout;
      int r1 = R + m + 1; if (r1 > capA) r1 = capA;
      int r0 = R + m;     if (r0 > Wout) r0 = Wout;
      short8 a1[2], a0[2];
      afrag2(rb, r1, kh, a1);
      afrag2(rb, r0, kh, a0);
      float cinit[16];                      // rb[row+1] residual carry (phase3)
      #pragma unroll
      for (int r = 0; r < 16; r++) {
        int row = (r & 3) + 8 * (r >> 2) + 4 * kh;
        int rr = R + row + 1; if (rr > Wout) rr = Wout;
        cinit[r] = b2f(rb[rr * 32 + m]);
      }
      float16 Fa, Fb, Ga, Gb;
      const float bf = bs[32 + m], bg = bs[64 + m];
      #pragma unroll
      for (int r = 0; r < 16; r++) { Fa[r] = bf; Fb[r] = 0.f; Ga[r] = bg; Gb[r] = 0.f; }
      Fa = MFMA_B16(a1[0], BW[0][0], Fa);
      Fa = MFMA_B16(a1[1], BW[0][1], Fa);
      Fb = MFMA_B16(a0[0], BW[1][0], Fb);
      Fb = MFMA_B16(a0[1], BW[1][1], Fb);
      Ga = MFMA_B16(a1[0], BW[2][0], Ga);
      Ga = MFMA_B16(a1[1], BW[2][1], Ga);
      Gb = MFMA_B16(a0[0], BW[3][0], Gb);
      Gb = MFMA_B16(a0[1], BW[3][1], Gb);
      #pragma unroll
      for (int r = 0; r < 16; r++) {
        int row = (r & 3) + 8 * (r >> 2) + 4 * kh;
        int uf = R + row;
        if (row < 31 && uf < Wout) {
          float u = __expf(-2.f * (Fa[r] + Fb[r]));
          float v = __expf(-(Ga[r] + Gb[r]));
          float fg = (1.f - u) * __builtin_amdgcn_rcpf((1.f + u) * (1.f + v));
          xm[uf * 32 + m] = f2bs(fg);
        }
      }
      asm volatile("s_waitcnt lgkmcnt(0)" ::: "memory");  // wave-local P2->P3

      // ---- phase3: xnext = rbias + R@xmid + cinit (own-tile xm) ----
      const int capX = (R + 30 < Wout - 1) ? (R + 30) : (Wout - 1);
      int rx = R + m; if (rx > capX) rx = capX;
      short8 aX[2];
      afrag2(xm, rx, kh, aX);
      float16 accX;
      const float br = bs[96 + m];
      #pragma unroll
      for (int r = 0; r < 16; r++) accX[r] = br + cinit[r];
      accX = MFMA_B16(aX[0], BW[4][0], accX);
      accX = MFMA_B16(aX[1], BW[4][1], accX);
      #pragma unroll
      for (int r = 0; r < 16; r++) {
        int row = (r & 3) + 8 * (r >> 2) + 4 * kh;
        int uf = R + row;
        if (row < 31 && uf < Wout) xout[uf * 32 + m] = f2bs(accX[r]);
      }
    } else if (newpf) {
      short* dst = bfw[(i + 1) & 1];
      #pragma unroll
      for (int q = 0; q < 7; q++) {
        int c = ptid + q * nP;
        if (c < 896) {
          short8 v;
          #pragma unroll
          for (int j = 0; j < 8; j++) v[j] = f2bs(pfn[q][j]);
          *(short8*)&dst[c * 8] = v;
        }
      }
      for (int t2 = ptid; t2 < 128; t2 += nP) {
        const float* bsrc = (t2 < 32) ? dil_b : (t2 < 64) ? filt_b : (t2 < 96) ? gate_b : res_b;
        bias2[(i + 1) & 1][t2] = bsrc[(i + 1) * 32 + (t2 & 31)];
      }
    }

    if (oldpf) {
      short* dst = bfw[(i + 1) & 1];
      #pragma unroll
      for (int q = 0; q < 4; q++) {
        if (q < nch) {
          short8 v;
          #pragma unroll
          for (int j = 0; j < 8; j++) v[j] = f2bs(pfo[q][j]);
          *(short8*)&dst[(tid + q * NT) * 8] = v;
        }
      }
      if (tid < 128) bias2[(i + 1) & 1][tid] = pbias;
    }
    __syncthreads();                        // single barrier per layer
    Win = Wout;
  }

  // ---- layers 10..15: in-register pipeline on wave 0 ----
  {
    const int t31 = lane & 31;
    const int hb  = lane & 32;
    const int lx32 = lane ^ 32;
    unsigned xcur[8], e32[8], e33[8];
    int mode = 2;
    if (wv == 0) {
      const short* xb0 = xbuf[0];          // L9 wrote xbuf[0]
      int tcl = t31 < Win - 1 ? t31 : Win - 1;
      ldrow(xb0, tcl, kh, xcur);
      ldrow(xb0, 32, kh, e32);
      ldrow(xb0, 33, kh, e33);
      // probe permlane32_swap semantics exactly; fallback to shfl otherwise
      {
        unsigned pa = (unsigned)lane;
        unsigned pb = 64u + (unsigned)lane;
        uv2 pr = __builtin_amdgcn_permlane32_swap(pa, pb, false, false);
        unsigned x0  = (unsigned)__shfl((int)pr[0], 0);
        unsigned x32 = (unsigned)__shfl((int)pr[0], 32);
        unsigned y0  = (unsigned)__shfl((int)pr[1], 0);
        unsigned y32 = (unsigned)__shfl((int)pr[1], 32);
        if      (x0 == 0u  && x32 == 64u && y0 == 32u && y32 == 96u) mode = 0;
        else if (y0 == 0u  && y32 == 64u && x0 == 32u && x32 == 96u) mode = 1;
      }
    }

    #pragma unroll
    for (int i = 10; i < LL; i++) {
      const int d = 1 << (i & 3);
      const int Wout = Win - d - 1;
      // slot map: 10->bfw[0],11->bfw[1],12->bfw[0],13->bfw[1],14->pool,15->bfw[0]
      const short* bw = (i == 14) ? l14w : (i == 15) ? bfw[0] : bfw[i & 1];
      const float* bs = (i == 14) ? l14b : (i == 15) ? bias2[0] : bias2[i & 1];

      if (wv >= 1) {
        const int ptid = tid - 64;
        if (i == 10) {
          float pfA[5][8], pfB[5][8];
          #pragma unroll
          for (int q = 0; q < 5; q++) {
            int c = ptid + q * 192;
            if (c < 896) load_chunk(11, c, pfA[q], dil_w, filt_w, gate_w, res_w);
          }
          #pragma unroll
          for (int q = 0; q < 5; q++) {
            int c = ptid + q * 192;
            if (c < 896) load_chunk(14, c, pfB[q], dil_w, filt_w, gate_w, res_w);
          }
          #pragma unroll
          for (int q = 0; q < 5; q++) {
            int c = ptid + q * 192;
            if (c < 896) {
              short8 vA, vB;
              #pragma unroll
              for (int j = 0; j < 8; j++) { vA[j] = f2bs(pfA[q][j]); vB[j] = f2bs(pfB[q][j]); }
              *(short8*)&bfw[1][c * 8] = vA;
              *(short8*)&l14w[c * 8]   = vB;
            }
          }
          for (int t2 = ptid; t2 < 128; t2 += 192) {
            const float* bsrc = (t2 < 32) ? dil_b : (t2 < 64) ? filt_b : (t2 < 96) ? gate_b : res_b;
            bias2[1][t2] = bsrc[11 * 32 + (t2 & 31)];
            l14b[t2]     = bsrc[14 * 32 + (t2 & 31)];
          }
        } else if (i == 11) {
          stage_layer(12, ptid, bfw[0], bias2[0], dil_w, filt_w, gate_w, res_w,
                      dil_b, filt_b, gate_b, res_b);
        } else if (i == 12) {
          stage_layer(13, ptid, bfw[1], bias2[1], dil_w, filt_w, gate_w, res_w,
                      dil_b, filt_b, gate_b, res_b);
        } else if (i == 13) {
          stage_layer(15, ptid, bfw[0], bias2[0], dil_w, filt_w, gate_w, res_w,
                      dil_b, filt_b, gate_b, res_b);
        }
        // tail weight/bias warming (read-only; keeps L2/L3 hot for the tail)
        float ws = warm_lines(i - 10, ptid, end1_w, end2_w, fc1_w, fc2_w,
                              fc3_w, fc4_w, skip_w);
        if (i == 15) ws += warm_bias(ptid, end1_b, end2_b, fc1_b, fc2_b,
                                     fc3_b, fc4_b, skip_b);
        asm volatile("" :: "v"(ws));       // keep loads live (no DCE)
      }

      if (wv == 0) {
        short8 WA[7][2];
        #pragma unroll
        for (int mt = 0; mt < 7; mt++)
          #pragma unroll
          for (int h = 0; h < 2; h++)
            WA[mt][h] = *(const short8*)&bw[((mt * 2 + h) * 64 + lane) * 8];

        // ---- phase1 (2+2 split: W1.x[t] chain independent of shuffled tap) ----
        unsigned xd[8];
        if (i == 10) {
          int td = t31 + d;                 // d=4: lanes 28..31 -> 32..35
          int ts = td > 31 ? 31 : td;
          #pragma unroll
          for (int q = 0; q < 8; q++) {
            unsigned s = (unsigned)__shfl((int)xcur[q], hb | ts);
            s = (td == 32) ? e32[q] : s;
            s = (td >= 33) ? e33[q] : s;    // clamp Win-1 = 33
            xd[q] = s;
          }
        } else {
          int td = t31 + d; if (td > Win - 1) td = Win - 1;
          int srcd = hb | td;
          #pragma unroll
          for (int q = 0; q < 8; q++) xd[q] = (unsigned)__shfl((int)xcur[q], srcd);
        }
        float16 p1a, p1b;
        #pragma unroll
        for (int g = 0; g < 4; g++) {
          float4 b4 = *(const float4*)&bs[4 * kh + 8 * g];
          p1a[4*g+0] = b4.x; p1a[4*g+1] = b4.y; p1a[4*g+2] = b4.z; p1a[4*g+3] = b4.w;
          p1b[4*g+0] = 0.f;  p1b[4*g+1] = 0.f;  p1b[4*g+2] = 0.f;  p1b[4*g+3] = 0.f;
        }
        p1a = MFMA_B16(WA[1][0], mk8(xcur[0], xcur[1], xcur[2], xcur[3]), p1a);
        p1a = MFMA_B16(WA[1][1], mk8(xcur[4], xcur[5], xcur[6], xcur[7]), p1a);
        p1b = MFMA_B16(WA[0][0], mk8(xd[0], xd[1], xd[2], xd[3]), p1b);
        p1b = MFMA_B16(WA[0][1], mk8(xd[4], xd[5], xd[6], xd[7]), p1b);

        unsigned rb0w[8];
        #pragma unroll
        for (int q = 0; q < 8; q++)
          rb0w[q] = cvtpk(p1a[2 * q] + p1b[2 * q], p1a[2 * q + 1] + p1b[2 * q + 1]);
        exch(rb0w, kh, lx32, mode);
        int t1 = t31 + 1; if (t1 > Wout) t1 = Wout;
        int s1o = hb | t1;
        unsigned rb1w[8];
        #pragma unroll
        for (int q = 0; q < 8; q++) rb1w[q] = (unsigned)__shfl((int)rb0w[q], s1o);

        // ---- phase2 (2+2 splits; rb0 chains independent of shift round) ----
        float16 Fa, Fb, Ga, Gb;
        #pragma unroll
        for (int g = 0; g < 4; g++) {
          float4 bF = *(const float4*)&bs[32 + 4 * kh + 8 * g];
          float4 bG = *(const float4*)&bs[64 + 4 * kh + 8 * g];
          Fa[4*g+0] = bF.x; Fa[4*g+1] = bF.y; Fa[4*g+2] = bF.z; Fa[4*g+3] = bF.w;
          Ga[4*g+0] = bG.x; Ga[4*g+1] = bG.y; Ga[4*g+2] = bG.z; Ga[4*g+3] = bG.w;
          Fb[4*g+0] = 0.f; Fb[4*g+1] = 0.f; Fb[4*g+2] = 0.f; Fb[4*g+3] = 0.f;
          Gb[4*g+0] = 0.f; Gb[4*g+1] = 0.f; Gb[4*g+2] = 0.f; Gb[4*g+3] = 0.f;
        }
        short8 RB00 = mk8(rb0w[0], rb0w[1], rb0w[2], rb0w[3]);
        short8 RB01 = mk8(rb0w[4], rb0w[5], rb0w[6], rb0w[7]);
        short8 RB10 = mk8(rb1w[0], rb1w[1], rb1w[2], rb1w[3]);
        short8 RB11 = mk8(rb1w[4], rb1w[5], rb1w[6], rb1w[7]);
        Fa = MFMA_B16(WA[3][0], RB00, Fa);
        Fa = MFMA_B16(WA[3][1], RB01, Fa);
        Ga = MFMA_B16(WA[5][0], RB00, Ga);
        Ga = MFMA_B16(WA[5][1], RB01, Ga);
        Fb = MFMA_B16(WA[2][0], RB10, Fb);
        Fb = MFMA_B16(WA[2][1], RB11, Fb);
        Gb = MFMA_B16(WA[4][0], RB10, Gb);
        Gb = MFMA_B16(WA[4][1], RB11, Gb);
        float fg[16];
        #pragma unroll
        for (int r = 0; r < 16; r++) {
          float u = __expf(-2.f * (Fa[r] + Fb[r]));
          float v = __expf(-(Ga[r] + Gb[r]));
          fg[r] = (1.f - u) * __builtin_amdgcn_rcpf((1.f + u) * (1.f + v));
        }
        unsigned wxm[8];
        #pragma unroll
        for (int q = 0; q < 8; q++) wxm[q] = cvtpk(fg[2 * q], fg[2 * q + 1]);

        if (i == LL - 1) {
          if (t31 == 0) {
            #pragma unroll
            for (int q = 0; q < 8; q++) {
              int c0 = (2 * q & 3) + 8 * (q >> 1) + 4 * kh;
              *(unsigned*)&xbuf[0][c0] = wxm[q];
            }
          }
        } else {
          // ---- phase3: xnext = rbias + Wr.xm + residual[t+1] ----
          unsigned x1[8];
          #pragma unroll
          for (int q = 0; q < 8; q++) x1[q] = rb1w[q];
          exch(x1, kh, lx32, mode);
          unsigned xmw[8];
          #pragma unroll
          for (int q = 0; q < 8; q++) xmw[q] = wxm[q];
          exch(xmw, kh, lx32, mode);
          float16 accX;
          #pragma unroll
          for (int g = 0; g < 4; g++) {
            float4 bR = *(const float4*)&bs[96 + 4 * kh + 8 * g];
            #pragma unroll
            for (int j = 0; j < 4; j++) {
              int r = 4 * g + j;
              unsigned w = x1[r >> 1];
              float rv = (r & 1) ? u2f(w & 0xFFFF0000u) : u2f(w << 16);
              accX[r] = ((const float*)&bR)[j] + rv;
            }
          }
          accX = MFMA_B16(WA[6][0], mk8(xmw[0], xmw[1], xmw[2], xmw[3]), accX);
          accX = MFMA_B16(WA[6][1], mk8(xmw[4], xmw[5], xmw[6], xmw[7]), accX);
          #pragma unroll
          for (int q = 0; q < 8; q++) xcur[q] = cvtpk(accX[2 * q], accX[2 * q + 1]);
          exch(xcur, kh, lx32, mode);
        }
      }
      if (i <= 13) __syncthreads();
      Win = Wout;
    }
  }
  __syncthreads();   // xbuf[0] spill handoff to all waves

  // ---- tail: coalesced skip (8-way split-K) + 6 split-K stages ----
  {
    const short* xmt = xbuf[0];
    const int s8 = tid & 7, rb8 = tid >> 3;
    const int ro = rb8 + 32 * s8;
    const float sb = skip_b[15 * 256 + ro];   // hoisted bias
    float xv[4];
    #pragma unroll
    for (int j = 0; j < 4; j++) xv[j] = b2f(xmt[s8 * 4 + j]);
    float part[8];
    #pragma unroll
    for (int p = 0; p < 8; p++) {
      const float* wr = skip_w + (15 * 256 + rb8 + 32 * p) * 32 + s8 * 4;
      float4 w = *(const float4*)wr;
      part[p] = (w.x * xv[0] + w.y * xv[1]) + (w.z * xv[2] + w.w * xv[3]);
    }
    #pragma unroll
    for (int p = 0; p < 8; p++) part[p] = row8_sum(part[p], dpp);
    float val = part[0];
    #pragma unroll
    for (int p = 1; p < 8; p++) val = (s8 == p) ? part[p] : val;
    vecA[ro] = fmaxf(val + sb, 0.f);
  }
  __syncthreads();
  mv_stage<256, 256, true >(end1_w, end1_b, vecA, vecB, tid, dpp);
  __syncthreads();
  mv_stage<256, 256, false>(end2_w, end2_b, vecB, vecA, tid, dpp);
  __syncthreads();
  mv_stage<128, 256, true >(fc1_w, fc1_b, vecA, vecB, tid, dpp);
  __syncthreads();
  mv_stage<128, 128, true >(fc2_w, fc2_b, vecB, vecA, tid, dpp);
  __syncthreads();
  mv_stage< 64, 128, true >(fc3_w, fc3_b, vecA, vecB, tid, dpp);
  __syncthreads();
  mv_stage<256,  64, false>(fc4_w, fc4_b, vecB, out + b * 256, tid, dpp);
}

extern "C" void kernel_launch(void* const* d_in, const int* in_sizes, int n_in,
                              void* d_out, int out_size, void* d_ws, size_t ws_size,
                              hipStream_t stream) {
  wavenet_kernel<<<BB, NT, 0, stream>>>(
      (const int*)d_in[0],    (const float*)d_in[1],  (const float*)d_in[2],  (const float*)d_in[3],
      (const float*)d_in[4],  (const float*)d_in[5],  (const float*)d_in[6],  (const float*)d_in[7],
      (const float*)d_in[8],  (const float*)d_in[9],  (const float*)d_in[10], (const float*)d_in[11],
      (const float*)d_in[12], (const float*)d_in[13], (const float*)d_in[14], (const float*)d_in[15],
      (const float*)d_in[16], (const float*)d_in[17], (const float*)d_in[18], (const float*)d_in[19],
      (const float*)d_in[20], (const float*)d_in[21], (const float*)d_in[22], (const float*)d_in[23],
      (const float*)d_in[24], (const float*)d_in[25], (float*)d_out);
}

// Round 9
// 194.215 us; speedup vs baseline: 1.0137x; 1.0137x over previous
//
#include <hip/hip_runtime.h>

// WaveNet inference on MFMA. Exploits: (1) only last timestep feeds the FC
// head, (2) skip overwritten each layer (only layer 15's matters),
// (3) receptive field at t=T-1 is 77 steps.
// Round 22 = R20 (warming reverted; R21 showed tail is TA-throughput bound,
// warming doubles TA work) + bias hoist (kept from R21) +
// TRIPLE-BUFFERED WEIGHT SLOTS (bfw[3], slot=i%3) with 2-layer-ahead
// staging: during layer i, compute waves READ slot i%3, PREFETCH layer
// i+1's 14 b128 frags from slot (i+1)%3 (stable: written during i-1),
// staging writes slot (i+2)%3 (dead since i-1). Removes ~14 dependent
// ds_read_b128 from every layer-top chain (16 layers). L0+L1 staged at
// top; L0 frags prefetched during init conv. l14/l15 special slots gone.
// Regime rules learned (R3/4: >256 thr spills; R8: never trade CUs for
// waves; R9/R11: no serial work to kill barriers; R12: reg plumbing ~ LDS;
// R14: staging off compute waves ~neutral; R15/R16: dependent hops on the
// critical wave are the chain; R17: never ship unverifiable asm semantics;
// R19: tail weight-read coalescing -8%; R20: reduce flavor neutral;
// R21: warming regressed -> tail is TA-bound, don't double-read).

#define BB 16
#define TT 8192
#define LL 16
#define W0 77
#define NT 256

typedef __attribute__((ext_vector_type(8)))  short short8;
typedef __attribute__((ext_vector_type(16))) float float16;
typedef __attribute__((ext_vector_type(2)))  unsigned uv2;

#define MFMA_B16(a, b, c) __builtin_amdgcn_mfma_f32_32x32x16_bf16(a, b, c, 0, 0, 0)

__device__ __forceinline__ short f2bs(float f) {   // f32 -> bf16 bits, RNE
  union { float ff; unsigned u; } v; v.ff = f;
  unsigned u = v.u;
  return (short)((u + 0x7FFFu + ((u >> 16) & 1u)) >> 16);
}
__device__ __forceinline__ float b2f(short h) {
  union { unsigned u; float f; } v;
  v.u = ((unsigned)(unsigned short)h) << 16; return v.f;
}
__device__ __forceinline__ unsigned cvtpk(float lo, float hi) {
  unsigned r;
  asm("v_cvt_pk_bf16_f32 %0, %1, %2" : "=v"(r) : "v"(lo), "v"(hi));
  return r;
}
__device__ __forceinline__ short8 mk8(unsigned a, unsigned b, unsigned c, unsigned d) {
  union { unsigned u[4]; short8 s; } z;
  z.u[0] = a; z.u[1] = b; z.u[2] = c; z.u[3] = d; return z.s;
}
__device__ __forceinline__ float u2f(unsigned u) {
  union { unsigned x; float f; } z; z.x = u; return z.f;
}

// DPP-assisted lane-group sums (probe-verified; shfl fallback).
__device__ __forceinline__ float dpp_add(float x, const int ctrl_sel) {
  int xi = __float_as_int(x);
  int m;
  if (ctrl_sel == 0)      m = __builtin_amdgcn_update_dpp(0, xi, 0xB1,  0xF, 0xF, true);
  else if (ctrl_sel == 1) m = __builtin_amdgcn_update_dpp(0, xi, 0x4E,  0xF, 0xF, true);
  else if (ctrl_sel == 2) m = __builtin_amdgcn_update_dpp(0, xi, 0x124, 0xF, 0xF, true);
  else if (ctrl_sel == 3) m = __builtin_amdgcn_update_dpp(0, xi, 0x128, 0xF, 0xF, true);
  else                    m = __builtin_amdgcn_update_dpp(0, xi, 0x141, 0xF, 0xF, true);
  return x + __int_as_float(m);
}
__device__ __forceinline__ float row16_sum(float x, bool dpp) {
  if (dpp) {
    x = dpp_add(x, 0); x = dpp_add(x, 1); x = dpp_add(x, 2); x = dpp_add(x, 3);
  } else {
    #pragma unroll
    for (int d2 = 1; d2 < 16; d2 <<= 1) x += __shfl_xor(x, d2);
  }
  return x;
}
__device__ __forceinline__ float row8_sum(float x, bool dpp) {
  if (dpp) {
    x = dpp_add(x, 0); x = dpp_add(x, 1); x = dpp_add(x, 4);
  } else {
    #pragma unroll
    for (int d2 = 1; d2 < 8; d2 <<= 1) x += __shfl_xor(x, d2);
  }
  return x;
}

// D'-words -> B-frag words via cross-half words cr (cr[q] = own[q] from l^32).
__device__ __forceinline__ void asmb(const unsigned* own, const unsigned* cr,
                                     int kh, unsigned* o) {
  #pragma unroll
  for (int h = 0; h < 2; h++) {
    o[4*h+0] = kh ? cr[4*h+2] : own[4*h+0];
    o[4*h+1] = kh ? cr[4*h+3] : own[4*h+1];
    o[4*h+2] = kh ? own[4*h+2] : cr[4*h+0];
    o[4*h+3] = kh ? own[4*h+3] : cr[4*h+1];
  }
}

// In-place half-exchange of 8 words. mode 0/1: permlane32_swap builtin
// (either return order); mode 2: __shfl fallback (exact R16 path).
__device__ __forceinline__ void exch(unsigned* o, int kh, int lx32, int mode) {
  if (mode < 2) {
    #pragma unroll
    for (int h = 0; h < 2; h++)
      #pragma unroll
      for (int j = 0; j < 2; j++) {
        unsigned A = o[4*h+j], C = o[4*h+2+j];
        uv2 r = __builtin_amdgcn_permlane32_swap(A, C, false, false);
        o[4*h+j]   = (mode == 0) ? r[0] : r[1];
        o[4*h+2+j] = (mode == 0) ? r[1] : r[0];
      }
  } else {
    unsigned cr[8];
    #pragma unroll
    for (int q = 0; q < 8; q++) cr[q] = (unsigned)__shfl((int)o[q], lx32);
    unsigned t[8];
    asmb(o, cr, kh, t);
    #pragma unroll
    for (int q = 0; q < 8; q++) o[q] = t[q];
  }
}

// A-fragment halves from [row][32] bf16 LDS: A[m][k], k-local=(lane>>5)*8+j.
__device__ __forceinline__ void afrag2(const short* src, int row, int kh, short8* out) {
  out[0] = *(const short8*)&src[row * 32 + 8 * kh];
  out[1] = *(const short8*)&src[row * 32 + 16 + 8 * kh];
}

// load a full row's 8 packed words (B-frag layout) from [row][32] bf16 LDS
__device__ __forceinline__ void ldrow(const short* xb, int row, int kh, unsigned* w8) {
  #pragma unroll
  for (int h = 0; h < 2; h++) {
    short8 v = *(const short8*)&xb[row * 32 + 16 * h + 8 * kh];
    union { short8 s; unsigned u[4]; } z; z.s = v;
    #pragma unroll
    for (int s = 0; s < 4; s++) w8[4 * h + s] = z.u[s];
  }
}

// load the 14 per-lane weight frags of one layer's buffer (B-frag indices;
// identical indices serve as A-frags of W^T in the reg path).
__device__ __forceinline__ void ldfrags(const short* bw, int lane, short8 PF[7][2]) {
  #pragma unroll
  for (int mt = 0; mt < 7; mt++)
    #pragma unroll
    for (int h = 0; h < 2; h++)
      PF[mt][h] = *(const short8*)&bw[((mt * 2 + h) * 64 + lane) * 8];
}

// chunk cid in [0,896): mat=cid>>7, h=(cid>>6)&1, ln=cid&63 -> n=ln&31,k2=ln>>5
__device__ __forceinline__ void load_chunk(
    int li, int cid, float* pf,
    const float* dil_w, const float* filt_w, const float* gate_w, const float* res_w)
{
  int mat = cid >> 7;
  int h = (cid >> 6) & 1, ln = cid & 63;
  int n = ln & 31, k2 = ln >> 5;
  int base = (li * 32 + n) * 32 + 16 * h + 8 * k2;
  if (mat == 6) {
    const float* p = res_w + base;
    #pragma unroll
    for (int j = 0; j < 8; j++) pf[j] = p[j];
  } else {
    const float* w = (mat < 2) ? dil_w : (mat < 4) ? filt_w : gate_w;
    const float* p = w + base * 2 + (mat & 1);
    #pragma unroll
    for (int j = 0; j < 8; j++) pf[j] = p[2 * j];
  }
}

// stage one layer's frags+bias (staging waves, ptid in [0,192))
__device__ __forceinline__ void stage_layer(
    int li, int ptid, short* dst, float* bdst,
    const float* dil_w, const float* filt_w, const float* gate_w, const float* res_w,
    const float* dil_b, const float* filt_b, const float* gate_b, const float* res_b)
{
  float pf[5][8];
  #pragma unroll
  for (int q = 0; q < 5; q++) {
    int c = ptid + q * 192;
    if (c < 896) load_chunk(li, c, pf[q], dil_w, filt_w, gate_w, res_w);
  }
  #pragma unroll
  for (int q = 0; q < 5; q++) {
    int c = ptid + q * 192;
    if (c < 896) {
      short8 v;
      #pragma unroll
      for (int j = 0; j < 8; j++) v[j] = f2bs(pf[q][j]);
      *(short8*)&dst[c * 8] = v;
    }
  }
  for (int t2 = ptid; t2 < 128; t2 += 192) {
    const float* bsrc = (t2 < 32) ? dil_b : (t2 < 64) ? filt_b : (t2 < 96) ? gate_b : res_b;
    bdst[t2] = bsrc[li * 32 + (t2 & 31)];
  }
}

// Coalesced split-K matvec stage: W[R][K] row-major, vin LDS f32[K].
// Bias load hoisted to stage top (off the post-reduce critical path).
template<int R, int K, bool RELU>
__device__ __forceinline__ void mv_stage(const float* __restrict__ W,
                                         const float* __restrict__ bias,
                                         const float* vin, float* vout,
                                         int tid, bool dpp)
{
  constexpr int J = K >> 6;                 // float4 groups per pass
  constexpr int P = R >> 4;                 // passes (rows/16)
  const int s = tid & 15, rb = tid >> 4;
  const int ro = rb + 16 * (s & (P - 1));   // in-bounds for all threads
  const float bb = bias[ro];                // hoisted bias (issued early)
  float4 vf[J];
  #pragma unroll
  for (int j = 0; j < J; j++) vf[j] = *(const float4*)&vin[(s + 16 * j) * 4];
  float part[P];
  #pragma unroll
  for (int p = 0; p < P; p++) {
    const float* wr = W + (rb + 16 * p) * K;
    float a = 0.f, c = 0.f;
    #pragma unroll
    for (int j = 0; j < J; j++) {
      float4 w = *(const float4*)&wr[(s + 16 * j) * 4];
      a += w.x * vf[j].x + w.y * vf[j].y;
      c += w.z * vf[j].z + w.w * vf[j].w;
    }
    part[p] = a + c;
  }
  #pragma unroll
  for (int p = 0; p < P; p++) part[p] = row16_sum(part[p], dpp);
  if (s < P) {
    float val = part[0];
    #pragma unroll
    for (int p = 1; p < P; p++) val = (s == p) ? part[p] : val;
    float r2 = val + bb;
    if (RELU) r2 = fmaxf(r2, 0.f);
    vout[ro] = r2;
  }
}

__global__ __launch_bounds__(NT, 1) void wavenet_kernel(
    const int* __restrict__ tokens,
    const float* __restrict__ emb,
    const float* __restrict__ init_w, const float* __restrict__ init_b,
    const float* __restrict__ dil_w,  const float* __restrict__ dil_b,
    const float* __restrict__ filt_w, const float* __restrict__ filt_b,
    const float* __restrict__ gate_w, const float* __restrict__ gate_b,
    const float* __restrict__ res_w,  const float* __restrict__ res_b,
    const float* __restrict__ skip_w, const float* __restrict__ skip_b,
    const float* __restrict__ end1_w, const float* __restrict__ end1_b,
    const float* __restrict__ end2_w, const float* __restrict__ end2_b,
    const float* __restrict__ fc1_w,  const float* __restrict__ fc1_b,
    const float* __restrict__ fc2_w,  const float* __restrict__ fc2_b,
    const float* __restrict__ fc3_w,  const float* __restrict__ fc3_b,
    const float* __restrict__ fc4_w,  const float* __restrict__ fc4_b,
    float* __restrict__ out)
{
  __shared__ __align__(16) short bfw[3][7168];   // weight frags, TRIPLE buffer
  __shared__ __align__(16) float bias2[3][128];
  __shared__ __align__(16) short xbuf[2][W0 * 32];  // activation double buffer
  __shared__ __align__(16) short pool[8624];     // emb stage (init) / rb+xm
  __shared__ int tok[W0];
  __shared__ __align__(16) float vecA[256], vecB[256];

  short* rb = pool;          // 76*32 (LDS layers)
  short* xm = pool + 2432;   // 76*32 (LDS layers)

  const int tid  = threadIdx.x;
  const int lane = tid & 63;
  const int wv   = tid >> 6;
  const int m    = lane & 31;
  const int kh   = lane >> 5;
  const int b    = blockIdx.x;

  short8 PF[7][2];           // prefetched next-layer weight frags

  // ---- probe DPP reduce semantics (uniform; exact integer sums) ----
  bool dpp;
  {
    float s16 = row16_sum((float)((tid & 15) + 1), true);   // want 136
    float s8v = row8_sum((float)((tid & 7) + 1), true);     // want 36
    dpp = (bool)__all((s16 == 136.0f) && (s8v == 36.0f));
  }

  // ---- tokens ----
  if (tid < W0) tok[tid] = tokens[b * TT + (TT - 1 - tid)];
  __syncthreads();

  // ---- stage emb rows (bf16, rows zero-padded to K=112) ----
  for (int cid = tid; cid < 77 * 14; cid += NT) {
    int u = cid / 14, s = cid % 14;
    const float* er = emb + tok[u] * 100 + s * 8;
    short8 v;
    if (s < 12) {
      #pragma unroll
      for (int j = 0; j < 8; j++) v[j] = f2bs(er[j]);
    } else if (s == 12) {
      #pragma unroll
      for (int j = 0; j < 4; j++) v[j] = f2bs(er[j]);
      #pragma unroll
      for (int j = 4; j < 8; j++) v[j] = 0;
    } else {
      #pragma unroll
      for (int j = 0; j < 8; j++) v[j] = 0;
    }
    *(short8*)&pool[u * 112 + s * 8] = v;
  }
  // stage L0 -> bfw[0] and L1 -> bfw[1] (all threads, 1792 chunks)
  for (int cid = tid; cid < 1792; cid += NT) {
    int li = (cid >= 896) ? 1 : 0;
    int c = cid - 896 * li;
    float pf[8];
    load_chunk(li, c, pf, dil_w, filt_w, gate_w, res_w);
    short8 v;
    #pragma unroll
    for (int j = 0; j < 8; j++) v[j] = f2bs(pf[j]);
    *(short8*)&bfw[li][c * 8] = v;
  }
  if (tid < 128) {
    const float* bsrc = (tid < 32) ? dil_b : (tid < 64) ? filt_b : (tid < 96) ? gate_b : res_b;
    bias2[0][tid] = bsrc[tid & 31];
    bias2[1][tid] = bsrc[32 + (tid & 31)];
  }
  __syncthreads();

  // ---- init conv (waves 0..2, one 32-row tile each, MFMA K=112, 4+3 split)
  //      + prefetch L0 frags (compute waves of layer 0 are exactly wv<3) ----
  if (wv < 3) {
    short8 bi[7];
    #pragma unroll
    for (int s = 0; s < 7; s++) {
      const float* p = init_w + m * 100 + s * 16 + kh * 8;
      short8 v;
      if (s < 6) {
        #pragma unroll
        for (int j = 0; j < 8; j++) v[j] = f2bs(p[j]);
      } else if (kh == 0) {
        #pragma unroll
        for (int j = 0; j < 4; j++) v[j] = f2bs(p[j]);
        #pragma unroll
        for (int j = 4; j < 8; j++) v[j] = 0;
      } else {
        #pragma unroll
        for (int j = 0; j < 8; j++) v[j] = 0;
      }
      bi[s] = v;
    }
    const float binit = init_b[m];
    const int R = wv * 32;
    int u = R + m; if (u > 76) u = 76;
    float16 accA, accB;
    #pragma unroll
    for (int r = 0; r < 16; r++) { accA[r] = binit; accB[r] = 0.f; }
    #pragma unroll
    for (int s = 0; s < 7; s++) {
      short8 a = *(const short8*)&pool[u * 112 + s * 16 + kh * 8];
      if (s < 4) accA = MFMA_B16(a, bi[s], accA);
      else       accB = MFMA_B16(a, bi[s], accB);
    }
    ldfrags(bfw[0], lane, PF);             // prefetch L0 frags
    #pragma unroll
    for (int r = 0; r < 16; r++) {
      int row = (r & 3) + 8 * (r >> 2) + 4 * kh;
      int uu = R + row;
      if (uu < W0) xbuf[0][uu * 32 + m] = f2bs(accA[r] + accB[r]);
    }
  }
  __syncthreads();

  // ---- layers 0..9 (LDS pipeline, stride-31 tiles, 1 barrier, slot=i%3) ----
  int Win = W0;
  for (int i = 0; i < 10; i++) {
    const int d = 1 << (i & 3);
    const int Wout = Win - d - 1;
    const int T = (Wout + 31) / 31;
    const float* bs = bias2[i % 3];
    const short* xin  = xbuf[i & 1];
    short* xout = xbuf[(i + 1) & 1];

    // staging of layer i+2 into slot (i+2)%3 (that slot is dead: layer i-1)
    float pfo[4][8];
    float pbias = 0.f;
    const int nch = (tid < 128) ? 4 : 3;   // 896 = 3*256 + 128
    const bool oldpf = (T >= 3);           // layers 0-2: all-thread staging
    if (oldpf) {
      #pragma unroll
      for (int q = 0; q < 4; q++) {
        if (q < nch)
          load_chunk(i + 2, tid + q * NT, pfo[q], dil_w, filt_w, gate_w, res_w);
      }
      if (tid < 128) {
        const float* bsrc = (tid < 32) ? dil_b : (tid < 64) ? filt_b : (tid < 96) ? gate_b : res_b;
        pbias = bsrc[(i + 2) * 32 + (tid & 31)];
      }
    }
    const bool newpf = (T <= 2) && (wv >= T);   // layers 3-9: staging waves
    const int nP = NT - T * 64;
    const int ptid = tid - T * 64;
    float pfn[7][8];
    if (newpf) {
      #pragma unroll
      for (int q = 0; q < 7; q++) {
        int c = ptid + q * nP;
        if (c < 896) load_chunk(i + 2, c, pfn[q], dil_w, filt_w, gate_w, res_w);
      }
    }

    if (wv < T) {
      const int R = wv * 31;
      // frags for layer i come from PF (prefetched during layer i-1)
      short8 B0[2], B1[2], BW[5][2];
      #pragma unroll
      for (int h = 0; h < 2; h++) { B0[h] = PF[0][h]; B1[h] = PF[1][h]; }
      #pragma unroll
      for (int mt = 0; mt < 5; mt++)
        #pragma unroll
        for (int h = 0; h < 2; h++) BW[mt][h] = PF[mt + 2][h];

      // ---- phase1: rb rows R..R+31 (2+2 split chains) ----
      int vra = R + m + d; if (vra > Win - 1) vra = Win - 1;
      int vrz = R + m;     if (vrz > Win - 1) vrz = Win - 1;
      short8 aA[2], aZ[2];
      afrag2(xin, vra, kh, aA);
      afrag2(xin, vrz, kh, aZ);
      float16 p1a, p1b;
      const float bc = bs[m];
      #pragma unroll
      for (int r = 0; r < 16; r++) { p1a[r] = bc; p1b[r] = 0.f; }
      p1a = MFMA_B16(aA[0], B0[0], p1a);
      p1a = MFMA_B16(aA[1], B0[1], p1a);
      p1b = MFMA_B16(aZ[0], B1[0], p1b);
      p1b = MFMA_B16(aZ[1], B1[1], p1b);
      #pragma unroll
      for (int r = 0; r < 16; r++) {
        int row = (r & 3) + 8 * (r >> 2) + 4 * kh;
        int vr = R + row;
        if (vr <= Wout) rb[vr * 32 + m] = f2bs(p1a[r] + p1b[r]);
      }
      asm volatile("s_waitcnt lgkmcnt(0)" ::: "memory");  // wave-local P1->P2

      // ---- phase2: f/g convs (2+2 splits); hoisted phase3 C-init ----
      const int capA = (R + 31 < Wout) ? (R + 31) : Wout;
      int r1 = R + m + 1; if (r1 > capA) r1 = capA;
      int r0 = R + m;     if (r0 > Wout) r0 = Wout;
      short8 a1[2], a0[2];
      afrag2(rb, r1, kh, a1);
      afrag2(rb, r0, kh, a0);
      float cinit[16];                      // rb[row+1] residual carry (phase3)
      #pragma unroll
      for (int r = 0; r < 16; r++) {
        int row = (r & 3) + 8 * (r >> 2) + 4 * kh;
        int rr = R + row + 1; if (rr > Wout) rr = Wout;
        cinit[r] = b2f(rb[rr * 32 + m]);
      }
      float16 Fa, Fb, Ga, Gb;
      const float bf = bs[32 + m], bg = bs[64 + m];
      #pragma unroll
      for (int r = 0; r < 16; r++) { Fa[r] = bf; Fb[r] = 0.f; Ga[r] = bg; Gb[r] = 0.f; }
      Fa = MFMA_B16(a1[0], BW[0][0], Fa);
      Fa = MFMA_B16(a1[1], BW[0][1], Fa);
      Fb = MFMA_B16(a0[0], BW[1][0], Fb);
      Fb = MFMA_B16(a0[1], BW[1][1], Fb);
      Ga = MFMA_B16(a1[0], BW[2][0], Ga);
      Ga = MFMA_B16(a1[1], BW[2][1], Ga);
      Gb = MFMA_B16(a0[0], BW[3][0], Gb);
      Gb = MFMA_B16(a0[1], BW[3][1], Gb);
      #pragma unroll
      for (int r = 0; r < 16; r++) {
        int row = (r & 3) + 8 * (r >> 2) + 4 * kh;
        int uf = R + row;
        if (row < 31 && uf < Wout) {
          float u = __expf(-2.f * (Fa[r] + Fb[r]));
          float v = __expf(-(Ga[r] + Gb[r]));
          float fg = (1.f - u) * __builtin_amdgcn_rcpf((1.f + u) * (1.f + v));
          xm[uf * 32 + m] = f2bs(fg);
        }
      }
      asm volatile("s_waitcnt lgkmcnt(0)" ::: "memory");  // wave-local P2->P3

      // ---- phase3: xnext = rbias + R@xmid + cinit; prefetch layer i+1 ----
      const int capX = (R + 30 < Wout - 1) ? (R + 30) : (Wout - 1);
      int rx = R + m; if (rx > capX) rx = capX;
      short8 aX[2];
      afrag2(xm, rx, kh, aX);
      ldfrags(bfw[(i + 1) % 3], lane, PF);  // overlaps phase3 MFMA + barrier
      float16 accX;
      const float br = bs[96 + m];
      #pragma unroll
      for (int r = 0; r < 16; r++) accX[r] = br + cinit[r];
      accX = MFMA_B16(aX[0], BW[4][0], accX);
      accX = MFMA_B16(aX[1], BW[4][1], accX);
      #pragma unroll
      for (int r = 0; r < 16; r++) {
        int row = (r & 3) + 8 * (r >> 2) + 4 * kh;
        int uf = R + row;
        if (row < 31 && uf < Wout) xout[uf * 32 + m] = f2bs(accX[r]);
      }
    } else if (newpf) {
      short* dst = bfw[(i + 2) % 3];
      #pragma unroll
      for (int q = 0; q < 7; q++) {
        int c = ptid + q * nP;
        if (c < 896) {
          short8 v;
          #pragma unroll
          for (int j = 0; j < 8; j++) v[j] = f2bs(pfn[q][j]);
          *(short8*)&dst[c * 8] = v;
        }
      }
      for (int t2 = ptid; t2 < 128; t2 += nP) {
        const float* bsrc = (t2 < 32) ? dil_b : (t2 < 64) ? filt_b : (t2 < 96) ? gate_b : res_b;
        bias2[(i + 2) % 3][t2] = bsrc[(i + 2) * 32 + (t2 & 31)];
      }
    }

    if (oldpf) {
      short* dst = bfw[(i + 2) % 3];
      #pragma unroll
      for (int q = 0; q < 4; q++) {
        if (q < nch) {
          short8 v;
          #pragma unroll
          for (int j = 0; j < 8; j++) v[j] = f2bs(pfo[q][j]);
          *(short8*)&dst[(tid + q * NT) * 8] = v;
        }
      }
      if (tid < 128) bias2[(i + 2) % 3][tid] = pbias;
    }
    __syncthreads();                        // single barrier per layer
    Win = Wout;
  }

  // ---- layers 10..15: in-register pipeline on wave 0 (slot=i%3) ----
  {
    const int t31 = lane & 31;
    const int hb  = lane & 32;
    const int lx32 = lane ^ 32;
    unsigned xcur[8], e32[8], e33[8];
    int mode = 2;
    if (wv == 0) {
      const short* xb0 = xbuf[0];          // L9 wrote xbuf[0]
      int tcl = t31 < Win - 1 ? t31 : Win - 1;
      ldrow(xb0, tcl, kh, xcur);
      ldrow(xb0, 32, kh, e32);
      ldrow(xb0, 33, kh, e33);
      // probe permlane32_swap semantics exactly; fallback to shfl otherwise
      {
        unsigned pa = (unsigned)lane;
        unsigned pb = 64u + (unsigned)lane;
        uv2 pr = __builtin_amdgcn_permlane32_swap(pa, pb, false, false);
        unsigned x0  = (unsigned)__shfl((int)pr[0], 0);
        unsigned x32 = (unsigned)__shfl((int)pr[0], 32);
        unsigned y0  = (unsigned)__shfl((int)pr[1], 0);
        unsigned y32 = (unsigned)__shfl((int)pr[1], 32);
        if      (x0 == 0u  && x32 == 64u && y0 == 32u && y32 == 96u) mode = 0;
        else if (y0 == 0u  && y32 == 64u && x0 == 32u && x32 == 96u) mode = 1;
      }
    }

    #pragma unroll
    for (int i = 10; i < LL; i++) {
      const int d = 1 << (i & 3);
      const int Wout = Win - d - 1;
      const float* bs = bias2[i % 3];

      // staging waves: stage layer i+2 into slot (i+2)%3 (dead since i-1)
      if (wv >= 1 && i <= 13) {
        const int ptid = tid - 64;
        stage_layer(i + 2, ptid, bfw[(i + 2) % 3], bias2[(i + 2) % 3],
                    dil_w, filt_w, gate_w, res_w, dil_b, filt_b, gate_b, res_b);
      }

      if (wv == 0) {
        // weight A-frags for layer i from PF (prefetched during layer i-1)
        short8 WA[7][2];
        #pragma unroll
        for (int mt = 0; mt < 7; mt++)
          #pragma unroll
          for (int h = 0; h < 2; h++) WA[mt][h] = PF[mt][h];

        // ---- phase1 (2+2 split: W1.x[t] chain independent of shuffled tap) ----
        unsigned xd[8];
        if (i == 10) {
          int td = t31 + d;                 // d=4: lanes 28..31 -> 32..35
          int ts = td > 31 ? 31 : td;
          #pragma unroll
          for (int q = 0; q < 8; q++) {
            unsigned s = (unsigned)__shfl((int)xcur[q], hb | ts);
            s = (td == 32) ? e32[q] : s;
            s = (td >= 33) ? e33[q] : s;    // clamp Win-1 = 33
            xd[q] = s;
          }
        } else {
          int td = t31 + d; if (td > Win - 1) td = Win - 1;
          int srcd = hb | td;
          #pragma unroll
          for (int q = 0; q < 8; q++) xd[q] = (unsigned)__shfl((int)xcur[q], srcd);
        }
        float16 p1a, p1b;
        #pragma unroll
        for (int g = 0; g < 4; g++) {
          float4 b4 = *(const float4*)&bs[4 * kh + 8 * g];
          p1a[4*g+0] = b4.x; p1a[4*g+1] = b4.y; p1a[4*g+2] = b4.z; p1a[4*g+3] = b4.w;
          p1b[4*g+0] = 0.f;  p1b[4*g+1] = 0.f;  p1b[4*g+2] = 0.f;  p1b[4*g+3] = 0.f;
        }
        p1a = MFMA_B16(WA[1][0], mk8(xcur[0], xcur[1], xcur[2], xcur[3]), p1a);
        p1a = MFMA_B16(WA[1][1], mk8(xcur[4], xcur[5], xcur[6], xcur[7]), p1a);
        p1b = MFMA_B16(WA[0][0], mk8(xd[0], xd[1], xd[2], xd[3]), p1b);
        p1b = MFMA_B16(WA[0][1], mk8(xd[4], xd[5], xd[6], xd[7]), p1b);

        unsigned rb0w[8];
        #pragma unroll
        for (int q = 0; q < 8; q++)
          rb0w[q] = cvtpk(p1a[2 * q] + p1b[2 * q], p1a[2 * q + 1] + p1b[2 * q + 1]);
        exch(rb0w, kh, lx32, mode);
        int t1 = t31 + 1; if (t1 > Wout) t1 = Wout;
        int s1o = hb | t1;
        unsigned rb1w[8];
        #pragma unroll
        for (int q = 0; q < 8; q++) rb1w[q] = (unsigned)__shfl((int)rb0w[q], s1o);

        // ---- phase2 (2+2 splits; rb0 chains independent of shift round) ----
        float16 Fa, Fb, Ga, Gb;
        #pragma unroll
        for (int g = 0; g < 4; g++) {
          float4 bF = *(const float4*)&bs[32 + 4 * kh + 8 * g];
          float4 bG = *(const float4*)&bs[64 + 4 * kh + 8 * g];
          Fa[4*g+0] = bF.x; Fa[4*g+1] = bF.y; Fa[4*g+2] = bF.z; Fa[4*g+3] = bF.w;
          Ga[4*g+0] = bG.x; Ga[4*g+1] = bG.y; Ga[4*g+2] = bG.z; Ga[4*g+3] = bG.w;
          Fb[4*g+0] = 0.f; Fb[4*g+1] = 0.f; Fb[4*g+2] = 0.f; Fb[4*g+3] = 0.f;
          Gb[4*g+0] = 0.f; Gb[4*g+1] = 0.f; Gb[4*g+2] = 0.f; Gb[4*g+3] = 0.f;
        }
        short8 RB00 = mk8(rb0w[0], rb0w[1], rb0w[2], rb0w[3]);
        short8 RB01 = mk8(rb0w[4], rb0w[5], rb0w[6], rb0w[7]);
        short8 RB10 = mk8(rb1w[0], rb1w[1], rb1w[2], rb1w[3]);
        short8 RB11 = mk8(rb1w[4], rb1w[5], rb1w[6], rb1w[7]);
        Fa = MFMA_B16(WA[3][0], RB00, Fa);
        Fa = MFMA_B16(WA[3][1], RB01, Fa);
        Ga = MFMA_B16(WA[5][0], RB00, Ga);
        Ga = MFMA_B16(WA[5][1], RB01, Ga);
        Fb = MFMA_B16(WA[2][0], RB10, Fb);
        Fb = MFMA_B16(WA[2][1], RB11, Fb);
        Gb = MFMA_B16(WA[4][0], RB10, Gb);
        Gb = MFMA_B16(WA[4][1], RB11, Gb);
        float fg[16];
        #pragma unroll
        for (int r = 0; r < 16; r++) {
          float u = __expf(-2.f * (Fa[r] + Fb[r]));
          float v = __expf(-(Ga[r] + Gb[r]));
          fg[r] = (1.f - u) * __builtin_amdgcn_rcpf((1.f + u) * (1.f + v));
        }
        unsigned wxm[8];
        #pragma unroll
        for (int q = 0; q < 8; q++) wxm[q] = cvtpk(fg[2 * q], fg[2 * q + 1]);

        // prefetch layer i+1 frags (buffer stable: staged during i-1)
        if (i < LL - 1) ldfrags(bfw[(i + 1) % 3], lane, PF);

        if (i == LL - 1) {
          if (t31 == 0) {
            #pragma unroll
            for (int q = 0; q < 8; q++) {
              int c0 = (2 * q & 3) + 8 * (q >> 1) + 4 * kh;
              *(unsigned*)&xbuf[0][c0] = wxm[q];
            }
          }
        } else {
          // ---- phase3: xnext = rbias + Wr.xm + residual[t+1] ----
          unsigned x1[8];
          #pragma unroll
          for (int q = 0; q < 8; q++) x1[q] = rb1w[q];
          exch(x1, kh, lx32, mode);
          unsigned xmw[8];
          #pragma unroll
          for (int q = 0; q < 8; q++) xmw[q] = wxm[q];
          exch(xmw, kh, lx32, mode);
          float16 accX;
          #pragma unroll
          for (int g = 0; g < 4; g++) {
            float4 bR = *(const float4*)&bs[96 + 4 * kh + 8 * g];
            #pragma unroll
            for (int j = 0; j < 4; j++) {
              int r = 4 * g + j;
              unsigned w = x1[r >> 1];
              float rv = (r & 1) ? u2f(w & 0xFFFF0000u) : u2f(w << 16);
              accX[r] = ((const float*)&bR)[j] + rv;
            }
          }
          accX = MFMA_B16(WA[6][0], mk8(xmw[0], xmw[1], xmw[2], xmw[3]), accX);
          accX = MFMA_B16(WA[6][1], mk8(xmw[4], xmw[5], xmw[6], xmw[7]), accX);
          #pragma unroll
          for (int q = 0; q < 8; q++) xcur[q] = cvtpk(accX[2 * q], accX[2 * q + 1]);
          exch(xcur, kh, lx32, mode);
        }
      }
      if (i <= 13) __syncthreads();
      Win = Wout;
    }
  }
  __syncthreads();   // xbuf[0] spill handoff to all waves

  // ---- tail: coalesced skip (8-way split-K) + 6 split-K stages ----
  {
    const short* xmt = xbuf[0];
    const int s8 = tid & 7, rb8 = tid >> 3;
    const int ro = rb8 + 32 * s8;
    const float sb = skip_b[15 * 256 + ro];   // hoisted bias
    float xv[4];
    #pragma unroll
    for (int j = 0; j < 4; j++) xv[j] = b2f(xmt[s8 * 4 + j]);
    float part[8];
    #pragma unroll
    for (int p = 0; p < 8; p++) {
      const float* wr = skip_w + (15 * 256 + rb8 + 32 * p) * 32 + s8 * 4;
      float4 w = *(const float4*)wr;
      part[p] = (w.x * xv[0] + w.y * xv[1]) + (w.z * xv[2] + w.w * xv[3]);
    }
    #pragma unroll
    for (int p = 0; p < 8; p++) part[p] = row8_sum(part[p], dpp);
    float val = part[0];
    #pragma unroll
    for (int p = 1; p < 8; p++) val = (s8 == p) ? part[p] : val;
    vecA[ro] = fmaxf(val + sb, 0.f);
  }
  __syncthreads();
  mv_stage<256, 256, true >(end1_w, end1_b, vecA, vecB, tid, dpp);
  __syncthreads();
  mv_stage<256, 256, false>(end2_w, end2_b, vecB, vecA, tid, dpp);
  __syncthreads();
  mv_stage<128, 256, true >(fc1_w, fc1_b, vecA, vecB, tid, dpp);
  __syncthreads();
  mv_stage<128, 128, true >(fc2_w, fc2_b, vecB, vecA, tid, dpp);
  __syncthreads();
  mv_stage< 64, 128, true >(fc3_w, fc3_b, vecA, vecB, tid, dpp);
  __syncthreads();
  mv_stage<256,  64, false>(fc4_w, fc4_b, vecB, out + b * 256, tid, dpp);
}

extern "C" void kernel_launch(void* const* d_in, const int* in_sizes, int n_in,
                              void* d_out, int out_size, void* d_ws, size_t ws_size,
                              hipStream_t stream) {
  wavenet_kernel<<<BB, NT, 0, stream>>>(
      (const int*)d_in[0],    (const float*)d_in[1],  (const float*)d_in[2],  (const float*)d_in[3],
      (const float*)d_in[4],  (const float*)d_in[5],  (const float*)d_in[6],  (const float*)d_in[7],
      (const float*)d_in[8],  (const float*)d_in[9],  (const float*)d_in[10], (const float*)d_in[11],
      (const float*)d_in[12], (const float*)d_in[13], (const float*)d_in[14], (const float*)d_in[15],
      (const float*)d_in[16], (const float*)d_in[17], (const float*)d_in[18], (const float*)d_in[19],
      (const float*)d_in[20], (const float*)d_in[21], (const float*)d_in[22], (const float*)d_in[23],
      (const float*)d_in[24], (const float*)d_in[25], (float*)d_out);
}

// Round 10
// 194.066 us; speedup vs baseline: 1.0145x; 1.0008x over previous
//
#include <hip/hip_runtime.h>

// WaveNet inference on MFMA. Exploits: (1) only last timestep feeds the FC
// head, (2) skip overwritten each layer (only layer 15's matters),
// (3) receptive field at t=T-1 is 77 steps.
// Round 23 = R22 + END1 WEIGHT PRELOAD-TO-REGISTERS: every thread preloads
// 48 of its 64 float4 end1-weight slices (192 VGPRs; capped below full 64
// to keep static pressure ~<430/512, no spill) at reg-path entry -- the
// ~15us of L10-15 compute hides the load latency, and the tail's biggest
// stage then runs mostly load-free. asm "memory" clobber pins the issue
// point (loads cannot sink past it). Indexing/add-order identical to
// mv_stage -> bit-identical numerics. Doubles as a measurement: delta
// calibrates the tail's load-stream share.
// Regime rules learned (R3/4: >256 thr spills; R8: never trade CUs for
// waves; R9/R11: no serial work to kill barriers; R12: reg plumbing ~ LDS;
// R14: staging off compute waves ~neutral; R15/R16: dependent hops on the
// critical wave are the chain; R17: never ship unverifiable asm semantics;
// R19: tail weight-read coalescing -8%; R20: reduce flavor neutral;
// R21: warming regressed (tail TA-bound, never double-read);
// R22: layer-top frag prefetch ~neutral (already hidden)).

#define BB 16
#define TT 8192
#define LL 16
#define W0 77
#define NT 256

typedef __attribute__((ext_vector_type(8)))  short short8;
typedef __attribute__((ext_vector_type(16))) float float16;
typedef __attribute__((ext_vector_type(2)))  unsigned uv2;

#define MFMA_B16(a, b, c) __builtin_amdgcn_mfma_f32_32x32x16_bf16(a, b, c, 0, 0, 0)

__device__ __forceinline__ short f2bs(float f) {   // f32 -> bf16 bits, RNE
  union { float ff; unsigned u; } v; v.ff = f;
  unsigned u = v.u;
  return (short)((u + 0x7FFFu + ((u >> 16) & 1u)) >> 16);
}
__device__ __forceinline__ float b2f(short h) {
  union { unsigned u; float f; } v;
  v.u = ((unsigned)(unsigned short)h) << 16; return v.f;
}
__device__ __forceinline__ unsigned cvtpk(float lo, float hi) {
  unsigned r;
  asm("v_cvt_pk_bf16_f32 %0, %1, %2" : "=v"(r) : "v"(lo), "v"(hi));
  return r;
}
__device__ __forceinline__ short8 mk8(unsigned a, unsigned b, unsigned c, unsigned d) {
  union { unsigned u[4]; short8 s; } z;
  z.u[0] = a; z.u[1] = b; z.u[2] = c; z.u[3] = d; return z.s;
}
__device__ __forceinline__ float u2f(unsigned u) {
  union { unsigned x; float f; } z; z.x = u; return z.f;
}

// DPP-assisted lane-group sums (probe-verified; shfl fallback).
__device__ __forceinline__ float dpp_add(float x, const int ctrl_sel) {
  int xi = __float_as_int(x);
  int m;
  if (ctrl_sel == 0)      m = __builtin_amdgcn_update_dpp(0, xi, 0xB1,  0xF, 0xF, true);
  else if (ctrl_sel == 1) m = __builtin_amdgcn_update_dpp(0, xi, 0x4E,  0xF, 0xF, true);
  else if (ctrl_sel == 2) m = __builtin_amdgcn_update_dpp(0, xi, 0x124, 0xF, 0xF, true);
  else if (ctrl_sel == 3) m = __builtin_amdgcn_update_dpp(0, xi, 0x128, 0xF, 0xF, true);
  else                    m = __builtin_amdgcn_update_dpp(0, xi, 0x141, 0xF, 0xF, true);
  return x + __int_as_float(m);
}
__device__ __forceinline__ float row16_sum(float x, bool dpp) {
  if (dpp) {
    x = dpp_add(x, 0); x = dpp_add(x, 1); x = dpp_add(x, 2); x = dpp_add(x, 3);
  } else {
    #pragma unroll
    for (int d2 = 1; d2 < 16; d2 <<= 1) x += __shfl_xor(x, d2);
  }
  return x;
}
__device__ __forceinline__ float row8_sum(float x, bool dpp) {
  if (dpp) {
    x = dpp_add(x, 0); x = dpp_add(x, 1); x = dpp_add(x, 4);
  } else {
    #pragma unroll
    for (int d2 = 1; d2 < 8; d2 <<= 1) x += __shfl_xor(x, d2);
  }
  return x;
}

// D'-words -> B-frag words via cross-half words cr (cr[q] = own[q] from l^32).
__device__ __forceinline__ void asmb(const unsigned* own, const unsigned* cr,
                                     int kh, unsigned* o) {
  #pragma unroll
  for (int h = 0; h < 2; h++) {
    o[4*h+0] = kh ? cr[4*h+2] : own[4*h+0];
    o[4*h+1] = kh ? cr[4*h+3] : own[4*h+1];
    o[4*h+2] = kh ? own[4*h+2] : cr[4*h+0];
    o[4*h+3] = kh ? own[4*h+3] : cr[4*h+1];
  }
}

// In-place half-exchange of 8 words. mode 0/1: permlane32_swap builtin
// (either return order); mode 2: __shfl fallback (exact R16 path).
__device__ __forceinline__ void exch(unsigned* o, int kh, int lx32, int mode) {
  if (mode < 2) {
    #pragma unroll
    for (int h = 0; h < 2; h++)
      #pragma unroll
      for (int j = 0; j < 2; j++) {
        unsigned A = o[4*h+j], C = o[4*h+2+j];
        uv2 r = __builtin_amdgcn_permlane32_swap(A, C, false, false);
        o[4*h+j]   = (mode == 0) ? r[0] : r[1];
        o[4*h+2+j] = (mode == 0) ? r[1] : r[0];
      }
  } else {
    unsigned cr[8];
    #pragma unroll
    for (int q = 0; q < 8; q++) cr[q] = (unsigned)__shfl((int)o[q], lx32);
    unsigned t[8];
    asmb(o, cr, kh, t);
    #pragma unroll
    for (int q = 0; q < 8; q++) o[q] = t[q];
  }
}

// A-fragment halves from [row][32] bf16 LDS: A[m][k], k-local=(lane>>5)*8+j.
__device__ __forceinline__ void afrag2(const short* src, int row, int kh, short8* out) {
  out[0] = *(const short8*)&src[row * 32 + 8 * kh];
  out[1] = *(const short8*)&src[row * 32 + 16 + 8 * kh];
}

// load a full row's 8 packed words (B-frag layout) from [row][32] bf16 LDS
__device__ __forceinline__ void ldrow(const short* xb, int row, int kh, unsigned* w8) {
  #pragma unroll
  for (int h = 0; h < 2; h++) {
    short8 v = *(const short8*)&xb[row * 32 + 16 * h + 8 * kh];
    union { short8 s; unsigned u[4]; } z; z.s = v;
    #pragma unroll
    for (int s = 0; s < 4; s++) w8[4 * h + s] = z.u[s];
  }
}

// load the 14 per-lane weight frags of one layer's buffer (B-frag indices;
// identical indices serve as A-frags of W^T in the reg path).
__device__ __forceinline__ void ldfrags(const short* bw, int lane, short8 PF[7][2]) {
  #pragma unroll
  for (int mt = 0; mt < 7; mt++)
    #pragma unroll
    for (int h = 0; h < 2; h++)
      PF[mt][h] = *(const short8*)&bw[((mt * 2 + h) * 64 + lane) * 8];
}

// chunk cid in [0,896): mat=cid>>7, h=(cid>>6)&1, ln=cid&63 -> n=ln&31,k2=ln>>5
__device__ __forceinline__ void load_chunk(
    int li, int cid, float* pf,
    const float* dil_w, const float* filt_w, const float* gate_w, const float* res_w)
{
  int mat = cid >> 7;
  int h = (cid >> 6) & 1, ln = cid & 63;
  int n = ln & 31, k2 = ln >> 5;
  int base = (li * 32 + n) * 32 + 16 * h + 8 * k2;
  if (mat == 6) {
    const float* p = res_w + base;
    #pragma unroll
    for (int j = 0; j < 8; j++) pf[j] = p[j];
  } else {
    const float* w = (mat < 2) ? dil_w : (mat < 4) ? filt_w : gate_w;
    const float* p = w + base * 2 + (mat & 1);
    #pragma unroll
    for (int j = 0; j < 8; j++) pf[j] = p[2 * j];
  }
}

// stage one layer's frags+bias (staging waves, ptid in [0,192))
__device__ __forceinline__ void stage_layer(
    int li, int ptid, short* dst, float* bdst,
    const float* dil_w, const float* filt_w, const float* gate_w, const float* res_w,
    const float* dil_b, const float* filt_b, const float* gate_b, const float* res_b)
{
  float pf[5][8];
  #pragma unroll
  for (int q = 0; q < 5; q++) {
    int c = ptid + q * 192;
    if (c < 896) load_chunk(li, c, pf[q], dil_w, filt_w, gate_w, res_w);
  }
  #pragma unroll
  for (int q = 0; q < 5; q++) {
    int c = ptid + q * 192;
    if (c < 896) {
      short8 v;
      #pragma unroll
      for (int j = 0; j < 8; j++) v[j] = f2bs(pf[q][j]);
      *(short8*)&dst[c * 8] = v;
    }
  }
  for (int t2 = ptid; t2 < 128; t2 += 192) {
    const float* bsrc = (t2 < 32) ? dil_b : (t2 < 64) ? filt_b : (t2 < 96) ? gate_b : res_b;
    bdst[t2] = bsrc[li * 32 + (t2 & 31)];
  }
}

// Coalesced split-K matvec stage: W[R][K] row-major, vin LDS f32[K].
// Bias load hoisted to stage top (off the post-reduce critical path).
template<int R, int K, bool RELU>
__device__ __forceinline__ void mv_stage(const float* __restrict__ W,
                                         const float* __restrict__ bias,
                                         const float* vin, float* vout,
                                         int tid, bool dpp)
{
  constexpr int J = K >> 6;                 // float4 groups per pass
  constexpr int P = R >> 4;                 // passes (rows/16)
  const int s = tid & 15, rb = tid >> 4;
  const int ro = rb + 16 * (s & (P - 1));   // in-bounds for all threads
  const float bb = bias[ro];                // hoisted bias (issued early)
  float4 vf[J];
  #pragma unroll
  for (int j = 0; j < J; j++) vf[j] = *(const float4*)&vin[(s + 16 * j) * 4];
  float part[P];
  #pragma unroll
  for (int p = 0; p < P; p++) {
    const float* wr = W + (rb + 16 * p) * K;
    float a = 0.f, c = 0.f;
    #pragma unroll
    for (int j = 0; j < J; j++) {
      float4 w = *(const float4*)&wr[(s + 16 * j) * 4];
      a += w.x * vf[j].x + w.y * vf[j].y;
      c += w.z * vf[j].z + w.w * vf[j].w;
    }
    part[p] = a + c;
  }
  #pragma unroll
  for (int p = 0; p < P; p++) part[p] = row16_sum(part[p], dpp);
  if (s < P) {
    float val = part[0];
    #pragma unroll
    for (int p = 1; p < P; p++) val = (s == p) ? part[p] : val;
    float r2 = val + bb;
    if (RELU) r2 = fmaxf(r2, 0.f);
    vout[ro] = r2;
  }
}

__global__ __launch_bounds__(NT, 1) void wavenet_kernel(
    const int* __restrict__ tokens,
    const float* __restrict__ emb,
    const float* __restrict__ init_w, const float* __restrict__ init_b,
    const float* __restrict__ dil_w,  const float* __restrict__ dil_b,
    const float* __restrict__ filt_w, const float* __restrict__ filt_b,
    const float* __restrict__ gate_w, const float* __restrict__ gate_b,
    const float* __restrict__ res_w,  const float* __restrict__ res_b,
    const float* __restrict__ skip_w, const float* __restrict__ skip_b,
    const float* __restrict__ end1_w, const float* __restrict__ end1_b,
    const float* __restrict__ end2_w, const float* __restrict__ end2_b,
    const float* __restrict__ fc1_w,  const float* __restrict__ fc1_b,
    const float* __restrict__ fc2_w,  const float* __restrict__ fc2_b,
    const float* __restrict__ fc3_w,  const float* __restrict__ fc3_b,
    const float* __restrict__ fc4_w,  const float* __restrict__ fc4_b,
    float* __restrict__ out)
{
  __shared__ __align__(16) short bfw[3][7168];   // weight frags, TRIPLE buffer
  __shared__ __align__(16) float bias2[3][128];
  __shared__ __align__(16) short xbuf[2][W0 * 32];  // activation double buffer
  __shared__ __align__(16) short pool[8624];     // emb stage (init) / rb+xm
  __shared__ int tok[W0];
  __shared__ __align__(16) float vecA[256], vecB[256];

  short* rb = pool;          // 76*32 (LDS layers)
  short* xm = pool + 2432;   // 76*32 (LDS layers)

  const int tid  = threadIdx.x;
  const int lane = tid & 63;
  const int wv   = tid >> 6;
  const int m    = lane & 31;
  const int kh   = lane >> 5;
  const int b    = blockIdx.x;

  short8 PF[7][2];           // prefetched next-layer weight frags

  // ---- probe DPP reduce semantics (uniform; exact integer sums) ----
  bool dpp;
  {
    float s16 = row16_sum((float)((tid & 15) + 1), true);   // want 136
    float s8v = row8_sum((float)((tid & 7) + 1), true);     // want 36
    dpp = (bool)__all((s16 == 136.0f) && (s8v == 36.0f));
  }

  // ---- tokens ----
  if (tid < W0) tok[tid] = tokens[b * TT + (TT - 1 - tid)];
  __syncthreads();

  // ---- stage emb rows (bf16, rows zero-padded to K=112) ----
  for (int cid = tid; cid < 77 * 14; cid += NT) {
    int u = cid / 14, s = cid % 14;
    const float* er = emb + tok[u] * 100 + s * 8;
    short8 v;
    if (s < 12) {
      #pragma unroll
      for (int j = 0; j < 8; j++) v[j] = f2bs(er[j]);
    } else if (s == 12) {
      #pragma unroll
      for (int j = 0; j < 4; j++) v[j] = f2bs(er[j]);
      #pragma unroll
      for (int j = 4; j < 8; j++) v[j] = 0;
    } else {
      #pragma unroll
      for (int j = 0; j < 8; j++) v[j] = 0;
    }
    *(short8*)&pool[u * 112 + s * 8] = v;
  }
  // stage L0 -> bfw[0] and L1 -> bfw[1] (all threads, 1792 chunks)
  for (int cid = tid; cid < 1792; cid += NT) {
    int li = (cid >= 896) ? 1 : 0;
    int c = cid - 896 * li;
    float pf[8];
    load_chunk(li, c, pf, dil_w, filt_w, gate_w, res_w);
    short8 v;
    #pragma unroll
    for (int j = 0; j < 8; j++) v[j] = f2bs(pf[j]);
    *(short8*)&bfw[li][c * 8] = v;
  }
  if (tid < 128) {
    const float* bsrc = (tid < 32) ? dil_b : (tid < 64) ? filt_b : (tid < 96) ? gate_b : res_b;
    bias2[0][tid] = bsrc[tid & 31];
    bias2[1][tid] = bsrc[32 + (tid & 31)];
  }
  __syncthreads();

  // ---- init conv (waves 0..2, one 32-row tile each, MFMA K=112, 4+3 split)
  //      + prefetch L0 frags (compute waves of layer 0 are exactly wv<3) ----
  if (wv < 3) {
    short8 bi[7];
    #pragma unroll
    for (int s = 0; s < 7; s++) {
      const float* p = init_w + m * 100 + s * 16 + kh * 8;
      short8 v;
      if (s < 6) {
        #pragma unroll
        for (int j = 0; j < 8; j++) v[j] = f2bs(p[j]);
      } else if (kh == 0) {
        #pragma unroll
        for (int j = 0; j < 4; j++) v[j] = f2bs(p[j]);
        #pragma unroll
        for (int j = 4; j < 8; j++) v[j] = 0;
      } else {
        #pragma unroll
        for (int j = 0; j < 8; j++) v[j] = 0;
      }
      bi[s] = v;
    }
    const float binit = init_b[m];
    const int R = wv * 32;
    int u = R + m; if (u > 76) u = 76;
    float16 accA, accB;
    #pragma unroll
    for (int r = 0; r < 16; r++) { accA[r] = binit; accB[r] = 0.f; }
    #pragma unroll
    for (int s = 0; s < 7; s++) {
      short8 a = *(const short8*)&pool[u * 112 + s * 16 + kh * 8];
      if (s < 4) accA = MFMA_B16(a, bi[s], accA);
      else       accB = MFMA_B16(a, bi[s], accB);
    }
    ldfrags(bfw[0], lane, PF);             // prefetch L0 frags
    #pragma unroll
    for (int r = 0; r < 16; r++) {
      int row = (r & 3) + 8 * (r >> 2) + 4 * kh;
      int uu = R + row;
      if (uu < W0) xbuf[0][uu * 32 + m] = f2bs(accA[r] + accB[r]);
    }
  }
  __syncthreads();

  // ---- layers 0..9 (LDS pipeline, stride-31 tiles, 1 barrier, slot=i%3) ----
  int Win = W0;
  for (int i = 0; i < 10; i++) {
    const int d = 1 << (i & 3);
    const int Wout = Win - d - 1;
    const int T = (Wout + 31) / 31;
    const float* bs = bias2[i % 3];
    const short* xin  = xbuf[i & 1];
    short* xout = xbuf[(i + 1) & 1];

    // staging of layer i+2 into slot (i+2)%3 (that slot is dead: layer i-1)
    float pfo[4][8];
    float pbias = 0.f;
    const int nch = (tid < 128) ? 4 : 3;   // 896 = 3*256 + 128
    const bool oldpf = (T >= 3);           // layers 0-2: all-thread staging
    if (oldpf) {
      #pragma unroll
      for (int q = 0; q < 4; q++) {
        if (q < nch)
          load_chunk(i + 2, tid + q * NT, pfo[q], dil_w, filt_w, gate_w, res_w);
      }
      if (tid < 128) {
        const float* bsrc = (tid < 32) ? dil_b : (tid < 64) ? filt_b : (tid < 96) ? gate_b : res_b;
        pbias = bsrc[(i + 2) * 32 + (tid & 31)];
      }
    }
    const bool newpf = (T <= 2) && (wv >= T);   // layers 3-9: staging waves
    const int nP = NT - T * 64;
    const int ptid = tid - T * 64;
    float pfn[7][8];
    if (newpf) {
      #pragma unroll
      for (int q = 0; q < 7; q++) {
        int c = ptid + q * nP;
        if (c < 896) load_chunk(i + 2, c, pfn[q], dil_w, filt_w, gate_w, res_w);
      }
    }

    if (wv < T) {
      const int R = wv * 31;
      // frags for layer i come from PF (prefetched during layer i-1)
      short8 B0[2], B1[2], BW[5][2];
      #pragma unroll
      for (int h = 0; h < 2; h++) { B0[h] = PF[0][h]; B1[h] = PF[1][h]; }
      #pragma unroll
      for (int mt = 0; mt < 5; mt++)
        #pragma unroll
        for (int h = 0; h < 2; h++) BW[mt][h] = PF[mt + 2][h];

      // ---- phase1: rb rows R..R+31 (2+2 split chains) ----
      int vra = R + m + d; if (vra > Win - 1) vra = Win - 1;
      int vrz = R + m;     if (vrz > Win - 1) vrz = Win - 1;
      short8 aA[2], aZ[2];
      afrag2(xin, vra, kh, aA);
      afrag2(xin, vrz, kh, aZ);
      float16 p1a, p1b;
      const float bc = bs[m];
      #pragma unroll
      for (int r = 0; r < 16; r++) { p1a[r] = bc; p1b[r] = 0.f; }
      p1a = MFMA_B16(aA[0], B0[0], p1a);
      p1a = MFMA_B16(aA[1], B0[1], p1a);
      p1b = MFMA_B16(aZ[0], B1[0], p1b);
      p1b = MFMA_B16(aZ[1], B1[1], p1b);
      #pragma unroll
      for (int r = 0; r < 16; r++) {
        int row = (r & 3) + 8 * (r >> 2) + 4 * kh;
        int vr = R + row;
        if (vr <= Wout) rb[vr * 32 + m] = f2bs(p1a[r] + p1b[r]);
      }
      asm volatile("s_waitcnt lgkmcnt(0)" ::: "memory");  // wave-local P1->P2

      // ---- phase2: f/g convs (2+2 splits); hoisted phase3 C-init ----
      const int capA = (R + 31 < Wout) ? (R + 31) : Wout;
      int r1 = R + m + 1; if (r1 > capA) r1 = capA;
      int r0 = R + m;     if (r0 > Wout) r0 = Wout;
      short8 a1[2], a0[2];
      afrag2(rb, r1, kh, a1);
      afrag2(rb, r0, kh, a0);
      float cinit[16];                      // rb[row+1] residual carry (phase3)
      #pragma unroll
      for (int r = 0; r < 16; r++) {
        int row = (r & 3) + 8 * (r >> 2) + 4 * kh;
        int rr = R + row + 1; if (rr > Wout) rr = Wout;
        cinit[r] = b2f(rb[rr * 32 + m]);
      }
      float16 Fa, Fb, Ga, Gb;
      const float bf = bs[32 + m], bg = bs[64 + m];
      #pragma unroll
      for (int r = 0; r < 16; r++) { Fa[r] = bf; Fb[r] = 0.f; Ga[r] = bg; Gb[r] = 0.f; }
      Fa = MFMA_B16(a1[0], BW[0][0], Fa);
      Fa = MFMA_B16(a1[1], BW[0][1], Fa);
      Fb = MFMA_B16(a0[0], BW[1][0], Fb);
      Fb = MFMA_B16(a0[1], BW[1][1], Fb);
      Ga = MFMA_B16(a1[0], BW[2][0], Ga);
      Ga = MFMA_B16(a1[1], BW[2][1], Ga);
      Gb = MFMA_B16(a0[0], BW[3][0], Gb);
      Gb = MFMA_B16(a0[1], BW[3][1], Gb);
      #pragma unroll
      for (int r = 0; r < 16; r++) {
        int row = (r & 3) + 8 * (r >> 2) + 4 * kh;
        int uf = R + row;
        if (row < 31 && uf < Wout) {
          float u = __expf(-2.f * (Fa[r] + Fb[r]));
          float v = __expf(-(Ga[r] + Gb[r]));
          float fg = (1.f - u) * __builtin_amdgcn_rcpf((1.f + u) * (1.f + v));
          xm[uf * 32 + m] = f2bs(fg);
        }
      }
      asm volatile("s_waitcnt lgkmcnt(0)" ::: "memory");  // wave-local P2->P3

      // ---- phase3: xnext = rbias + R@xmid + cinit; prefetch layer i+1 ----
      const int capX = (R + 30 < Wout - 1) ? (R + 30) : (Wout - 1);
      int rx = R + m; if (rx > capX) rx = capX;
      short8 aX[2];
      afrag2(xm, rx, kh, aX);
      ldfrags(bfw[(i + 1) % 3], lane, PF);  // overlaps phase3 MFMA + barrier
      float16 accX;
      const float br = bs[96 + m];
      #pragma unroll
      for (int r = 0; r < 16; r++) accX[r] = br + cinit[r];
      accX = MFMA_B16(aX[0], BW[4][0], accX);
      accX = MFMA_B16(aX[1], BW[4][1], accX);
      #pragma unroll
      for (int r = 0; r < 16; r++) {
        int row = (r & 3) + 8 * (r >> 2) + 4 * kh;
        int uf = R + row;
        if (row < 31 && uf < Wout) xout[uf * 32 + m] = f2bs(accX[r]);
      }
    } else if (newpf) {
      short* dst = bfw[(i + 2) % 3];
      #pragma unroll
      for (int q = 0; q < 7; q++) {
        int c = ptid + q * nP;
        if (c < 896) {
          short8 v;
          #pragma unroll
          for (int j = 0; j < 8; j++) v[j] = f2bs(pfn[q][j]);
          *(short8*)&dst[c * 8] = v;
        }
      }
      for (int t2 = ptid; t2 < 128; t2 += nP) {
        const float* bsrc = (t2 < 32) ? dil_b : (t2 < 64) ? filt_b : (t2 < 96) ? gate_b : res_b;
        bias2[(i + 2) % 3][t2] = bsrc[(i + 2) * 32 + (t2 & 31)];
      }
    }

    if (oldpf) {
      short* dst = bfw[(i + 2) % 3];
      #pragma unroll
      for (int q = 0; q < 4; q++) {
        if (q < nch) {
          short8 v;
          #pragma unroll
          for (int j = 0; j < 8; j++) v[j] = f2bs(pfo[q][j]);
          *(short8*)&dst[(tid + q * NT) * 8] = v;
        }
      }
      if (tid < 128) bias2[(i + 2) % 3][tid] = pbias;
    }
    __syncthreads();                        // single barrier per layer
    Win = Wout;
  }

  // ---- end1 weight preload to registers (48 of 64 f4/thread; latency
  //      hides under the whole reg path; "memory" clobber pins issue) ----
  const int s16 = tid & 15, rb16 = tid >> 4;
  float4 e1w[48];
  #pragma unroll
  for (int p = 0; p < 12; p++)
    #pragma unroll
    for (int j = 0; j < 4; j++)
      e1w[p * 4 + j] = *(const float4*)&end1_w[(rb16 + 16 * p) * 256 + (s16 + 16 * j) * 4];
  asm volatile("" ::: "memory");

  // ---- layers 10..15: in-register pipeline on wave 0 (slot=i%3) ----
  {
    const int t31 = lane & 31;
    const int hb  = lane & 32;
    const int lx32 = lane ^ 32;
    unsigned xcur[8], e32[8], e33[8];
    int mode = 2;
    if (wv == 0) {
      const short* xb0 = xbuf[0];          // L9 wrote xbuf[0]
      int tcl = t31 < Win - 1 ? t31 : Win - 1;
      ldrow(xb0, tcl, kh, xcur);
      ldrow(xb0, 32, kh, e32);
      ldrow(xb0, 33, kh, e33);
      // probe permlane32_swap semantics exactly; fallback to shfl otherwise
      {
        unsigned pa = (unsigned)lane;
        unsigned pb = 64u + (unsigned)lane;
        uv2 pr = __builtin_amdgcn_permlane32_swap(pa, pb, false, false);
        unsigned x0  = (unsigned)__shfl((int)pr[0], 0);
        unsigned x32 = (unsigned)__shfl((int)pr[0], 32);
        unsigned y0  = (unsigned)__shfl((int)pr[1], 0);
        unsigned y32 = (unsigned)__shfl((int)pr[1], 32);
        if      (x0 == 0u  && x32 == 64u && y0 == 32u && y32 == 96u) mode = 0;
        else if (y0 == 0u  && y32 == 64u && x0 == 32u && x32 == 96u) mode = 1;
      }
    }

    #pragma unroll
    for (int i = 10; i < LL; i++) {
      const int d = 1 << (i & 3);
      const int Wout = Win - d - 1;
      const float* bs = bias2[i % 3];

      // staging waves: stage layer i+2 into slot (i+2)%3 (dead since i-1)
      if (wv >= 1 && i <= 13) {
        const int ptid = tid - 64;
        stage_layer(i + 2, ptid, bfw[(i + 2) % 3], bias2[(i + 2) % 3],
                    dil_w, filt_w, gate_w, res_w, dil_b, filt_b, gate_b, res_b);
      }

      if (wv == 0) {
        // weight A-frags for layer i from PF (prefetched during layer i-1)
        short8 WA[7][2];
        #pragma unroll
        for (int mt = 0; mt < 7; mt++)
          #pragma unroll
          for (int h = 0; h < 2; h++) WA[mt][h] = PF[mt][h];

        // ---- phase1 (2+2 split: W1.x[t] chain independent of shuffled tap) ----
        unsigned xd[8];
        if (i == 10) {
          int td = t31 + d;                 // d=4: lanes 28..31 -> 32..35
          int ts = td > 31 ? 31 : td;
          #pragma unroll
          for (int q = 0; q < 8; q++) {
            unsigned s = (unsigned)__shfl((int)xcur[q], hb | ts);
            s = (td == 32) ? e32[q] : s;
            s = (td >= 33) ? e33[q] : s;    // clamp Win-1 = 33
            xd[q] = s;
          }
        } else {
          int td = t31 + d; if (td > Win - 1) td = Win - 1;
          int srcd = hb | td;
          #pragma unroll
          for (int q = 0; q < 8; q++) xd[q] = (unsigned)__shfl((int)xcur[q], srcd);
        }
        float16 p1a, p1b;
        #pragma unroll
        for (int g = 0; g < 4; g++) {
          float4 b4 = *(const float4*)&bs[4 * kh + 8 * g];
          p1a[4*g+0] = b4.x; p1a[4*g+1] = b4.y; p1a[4*g+2] = b4.z; p1a[4*g+3] = b4.w;
          p1b[4*g+0] = 0.f;  p1b[4*g+1] = 0.f;  p1b[4*g+2] = 0.f;  p1b[4*g+3] = 0.f;
        }
        p1a = MFMA_B16(WA[1][0], mk8(xcur[0], xcur[1], xcur[2], xcur[3]), p1a);
        p1a = MFMA_B16(WA[1][1], mk8(xcur[4], xcur[5], xcur[6], xcur[7]), p1a);
        p1b = MFMA_B16(WA[0][0], mk8(xd[0], xd[1], xd[2], xd[3]), p1b);
        p1b = MFMA_B16(WA[0][1], mk8(xd[4], xd[5], xd[6], xd[7]), p1b);

        unsigned rb0w[8];
        #pragma unroll
        for (int q = 0; q < 8; q++)
          rb0w[q] = cvtpk(p1a[2 * q] + p1b[2 * q], p1a[2 * q + 1] + p1b[2 * q + 1]);
        exch(rb0w, kh, lx32, mode);
        int t1 = t31 + 1; if (t1 > Wout) t1 = Wout;
        int s1o = hb | t1;
        unsigned rb1w[8];
        #pragma unroll
        for (int q = 0; q < 8; q++) rb1w[q] = (unsigned)__shfl((int)rb0w[q], s1o);

        // ---- phase2 (2+2 splits; rb0 chains independent of shift round) ----
        float16 Fa, Fb, Ga, Gb;
        #pragma unroll
        for (int g = 0; g < 4; g++) {
          float4 bF = *(const float4*)&bs[32 + 4 * kh + 8 * g];
          float4 bG = *(const float4*)&bs[64 + 4 * kh + 8 * g];
          Fa[4*g+0] = bF.x; Fa[4*g+1] = bF.y; Fa[4*g+2] = bF.z; Fa[4*g+3] = bF.w;
          Ga[4*g+0] = bG.x; Ga[4*g+1] = bG.y; Ga[4*g+2] = bG.z; Ga[4*g+3] = bG.w;
          Fb[4*g+0] = 0.f; Fb[4*g+1] = 0.f; Fb[4*g+2] = 0.f; Fb[4*g+3] = 0.f;
          Gb[4*g+0] = 0.f; Gb[4*g+1] = 0.f; Gb[4*g+2] = 0.f; Gb[4*g+3] = 0.f;
        }
        short8 RB00 = mk8(rb0w[0], rb0w[1], rb0w[2], rb0w[3]);
        short8 RB01 = mk8(rb0w[4], rb0w[5], rb0w[6], rb0w[7]);
        short8 RB10 = mk8(rb1w[0], rb1w[1], rb1w[2], rb1w[3]);
        short8 RB11 = mk8(rb1w[4], rb1w[5], rb1w[6], rb1w[7]);
        Fa = MFMA_B16(WA[3][0], RB00, Fa);
        Fa = MFMA_B16(WA[3][1], RB01, Fa);
        Ga = MFMA_B16(WA[5][0], RB00, Ga);
        Ga = MFMA_B16(WA[5][1], RB01, Ga);
        Fb = MFMA_B16(WA[2][0], RB10, Fb);
        Fb = MFMA_B16(WA[2][1], RB11, Fb);
        Gb = MFMA_B16(WA[4][0], RB10, Gb);
        Gb = MFMA_B16(WA[4][1], RB11, Gb);
        float fg[16];
        #pragma unroll
        for (int r = 0; r < 16; r++) {
          float u = __expf(-2.f * (Fa[r] + Fb[r]));
          float v = __expf(-(Ga[r] + Gb[r]));
          fg[r] = (1.f - u) * __builtin_amdgcn_rcpf((1.f + u) * (1.f + v));
        }
        unsigned wxm[8];
        #pragma unroll
        for (int q = 0; q < 8; q++) wxm[q] = cvtpk(fg[2 * q], fg[2 * q + 1]);

        // prefetch layer i+1 frags (buffer stable: staged during i-1)
        if (i < LL - 1) ldfrags(bfw[(i + 1) % 3], lane, PF);

        if (i == LL - 1) {
          if (t31 == 0) {
            #pragma unroll
            for (int q = 0; q < 8; q++) {
              int c0 = (2 * q & 3) + 8 * (q >> 1) + 4 * kh;
              *(unsigned*)&xbuf[0][c0] = wxm[q];
            }
          }
        } else {
          // ---- phase3: xnext = rbias + Wr.xm + residual[t+1] ----
          unsigned x1[8];
          #pragma unroll
          for (int q = 0; q < 8; q++) x1[q] = rb1w[q];
          exch(x1, kh, lx32, mode);
          unsigned xmw[8];
          #pragma unroll
          for (int q = 0; q < 8; q++) xmw[q] = wxm[q];
          exch(xmw, kh, lx32, mode);
          float16 accX;
          #pragma unroll
          for (int g = 0; g < 4; g++) {
            float4 bR = *(const float4*)&bs[96 + 4 * kh + 8 * g];
            #pragma unroll
            for (int j = 0; j < 4; j++) {
              int r = 4 * g + j;
              unsigned w = x1[r >> 1];
              float rv = (r & 1) ? u2f(w & 0xFFFF0000u) : u2f(w << 16);
              accX[r] = ((const float*)&bR)[j] + rv;
            }
          }
          accX = MFMA_B16(WA[6][0], mk8(xmw[0], xmw[1], xmw[2], xmw[3]), accX);
          accX = MFMA_B16(WA[6][1], mk8(xmw[4], xmw[5], xmw[6], xmw[7]), accX);
          #pragma unroll
          for (int q = 0; q < 8; q++) xcur[q] = cvtpk(accX[2 * q], accX[2 * q + 1]);
          exch(xcur, kh, lx32, mode);
        }
      }
      if (i <= 13) __syncthreads();
      Win = Wout;
    }
  }
  __syncthreads();   // xbuf[0] spill handoff to all waves

  // ---- tail: coalesced skip (8-way split-K) + 6 split-K stages ----
  {
    const short* xmt = xbuf[0];
    const int s8 = tid & 7, rb8 = tid >> 3;
    const int ro = rb8 + 32 * s8;
    const float sb = skip_b[15 * 256 + ro];   // hoisted bias
    float xv[4];
    #pragma unroll
    for (int j = 0; j < 4; j++) xv[j] = b2f(xmt[s8 * 4 + j]);
    float part[8];
    #pragma unroll
    for (int p = 0; p < 8; p++) {
      const float* wr = skip_w + (15 * 256 + rb8 + 32 * p) * 32 + s8 * 4;
      float4 w = *(const float4*)wr;
      part[p] = (w.x * xv[0] + w.y * xv[1]) + (w.z * xv[2] + w.w * xv[3]);
    }
    #pragma unroll
    for (int p = 0; p < 8; p++) part[p] = row8_sum(part[p], dpp);
    float val = part[0];
    #pragma unroll
    for (int p = 1; p < 8; p++) val = (s8 == p) ? part[p] : val;
    vecA[ro] = fmaxf(val + sb, 0.f);
  }
  __syncthreads();
  // ---- end1: mostly register-resident weights (p<12 from e1w) ----
  {
    const int s = s16, rbq = rb16;
    const int ro = rbq + 16 * s;
    const float bb = end1_b[ro];
    float4 vf[4];
    #pragma unroll
    for (int j = 0; j < 4; j++) vf[j] = *(const float4*)&vecA[(s + 16 * j) * 4];
    float part[16];
    #pragma unroll
    for (int p = 0; p < 12; p++) {
      float a = 0.f, c = 0.f;
      #pragma unroll
      for (int j = 0; j < 4; j++) {
        float4 w = e1w[p * 4 + j];
        a += w.x * vf[j].x + w.y * vf[j].y;
        c += w.z * vf[j].z + w.w * vf[j].w;
      }
      part[p] = a + c;
    }
    #pragma unroll
    for (int p = 12; p < 16; p++) {
      const float* wr = end1_w + (rbq + 16 * p) * 256;
      float a = 0.f, c = 0.f;
      #pragma unroll
      for (int j = 0; j < 4; j++) {
        float4 w = *(const float4*)&wr[(s + 16 * j) * 4];
        a += w.x * vf[j].x + w.y * vf[j].y;
        c += w.z * vf[j].z + w.w * vf[j].w;
      }
      part[p] = a + c;
    }
    #pragma unroll
    for (int p = 0; p < 16; p++) part[p] = row16_sum(part[p], dpp);
    float val = part[0];
    #pragma unroll
    for (int p = 1; p < 16; p++) val = (s == p) ? part[p] : val;
    vecB[ro] = fmaxf(val + bb, 0.f);
  }
  __syncthreads();
  mv_stage<256, 256, false>(end2_w, end2_b, vecB, vecA, tid, dpp);
  __syncthreads();
  mv_stage<128, 256, true >(fc1_w, fc1_b, vecA, vecB, tid, dpp);
  __syncthreads();
  mv_stage<128, 128, true >(fc2_w, fc2_b, vecB, vecA, tid, dpp);
  __syncthreads();
  mv_stage< 64, 128, true >(fc3_w, fc3_b, vecA, vecB, tid, dpp);
  __syncthreads();
  mv_stage<256,  64, false>(fc4_w, fc4_b, vecB, out + b * 256, tid, dpp);
}

extern "C" void kernel_launch(void* const* d_in, const int* in_sizes, int n_in,
                              void* d_out, int out_size, void* d_ws, size_t ws_size,
                              hipStream_t stream) {
  wavenet_kernel<<<BB, NT, 0, stream>>>(
      (const int*)d_in[0],    (const float*)d_in[1],  (const float*)d_in[2],  (const float*)d_in[3],
      (const float*)d_in[4],  (const float*)d_in[5],  (const float*)d_in[6],  (const float*)d_in[7],
      (const float*)d_in[8],  (const float*)d_in[9],  (const float*)d_in[10], (const float*)d_in[11],
      (const float*)d_in[12], (const float*)d_in[13], (const float*)d_in[14], (const float*)d_in[15],
      (const float*)d_in[16], (const float*)d_in[17], (const float*)d_in[18], (const float*)d_in[19],
      (const float*)d_in[20], (const float*)d_in[21], (const float*)d_in[22], (const float*)d_in[23],
      (const float*)d_in[24], (const float*)d_in[25], (float*)d_out);
}